// Round 9
// baseline (553.779 us; speedup 1.0000x reference)
//
#include <hip/hip_runtime.h>
#include <stdint.h>

#define D      512
#define NSTEP  128          // SRC steps == decoder steps (TGT-1)
#define EVOC   50000
#define VTILE  128
#define NBV    ((EVOC + VTILE - 1) / VTILE)   // 391
#define LDA_W  36           // A LDS row stride in u32 words (144 B, 16B-aligned)
#define LDB_W  129          // B LDS kw-row stride in u32 words (128 cols + 1 pad)

typedef unsigned int u32x4 __attribute__((ext_vector_type(4)));

// ---- int8 dot4 (v_dot4_i32_i8) ----
__device__ inline int sdot4(int a, int b, int c) {
#if __has_builtin(__builtin_amdgcn_sdot4)
    return __builtin_amdgcn_sdot4(a, b, c, false);
#else
    int r = c;
    r += (int)(int8_t)(a)       * (int)(int8_t)(b);
    r += (int)(int8_t)(a >> 8)  * (int)(int8_t)(b >> 8);
    r += (int)(int8_t)(a >> 16) * (int)(int8_t)(b >> 16);
    r += (int)(int8_t)(a >> 24) * (int)(int8_t)(b >> 24);
    return r;
#endif
}

__device__ inline uint32_t pack4(float a, float b, float c, float d, float inv) {
    return  ((uint32_t)(uint8_t)(int8_t)__float2int_rn(a * inv)) |
            ((uint32_t)(uint8_t)(int8_t)__float2int_rn(b * inv) << 8) |
            ((uint32_t)(uint8_t)(int8_t)__float2int_rn(c * inv) << 16) |
            ((uint32_t)(uint8_t)(int8_t)__float2int_rn(d * inv) << 24);
}

// ---- K0: per-row symmetric INT4 quantization of Whh_e / Whh_d ----
// Output layout [which][word w][row r]: word w covers cols 8w..8w+7 of row r.
// Nibble packing: byte b = (q[8w+b]&0xF) | (q[8w+b+4]&0xF)<<4, so that
//   (x&0xF0F0F0F0)      = bytes q[8w+4..7] * 16 (signed, exact)
//   ((x<<4)&0xF0F0F0F0) = bytes q[8w+0..3] * 16 (signed, exact)
// Consumer accumulates with sdot4 and does one exact >>4 at the end.
__global__ __launch_bounds__(64) void k_quant(
        const float* __restrict__ We, const float* __restrict__ Wd,
        uint32_t* __restrict__ q4, float* __restrict__ qsc) {
    int bid = blockIdx.x;                 // 0..1023
    int which = bid >> 9, row = bid & 511;
    const float* W = which ? Wd : We;
    int j = threadIdx.x;                  // word index, cols 8j..8j+7
    const float* src = W + (size_t)row * D + j * 8;
    float w[8];
    #pragma unroll
    for (int k = 0; k < 8; k++) w[k] = src[k];
    float m = 0.f;
    #pragma unroll
    for (int k = 0; k < 8; k++) m = fmaxf(m, fabsf(w[k]));
    for (int off = 32; off; off >>= 1) m = fmaxf(m, __shfl_xor(m, off));
    float inv = (m > 0.f) ? 7.f / m : 0.f;
    uint32_t word = 0;
    #pragma unroll
    for (int b = 0; b < 4; b++) {
        int qlo = __float2int_rn(w[b] * inv);
        int qhi = __float2int_rn(w[b + 4] * inv);
        qlo = max(-7, min(7, qlo));
        qhi = max(-7, min(7, qhi));
        word |= (((uint32_t)(qlo & 0xF)) | ((uint32_t)(qhi & 0xF) << 4)) << (8 * b);
    }
    q4[(size_t)which * (D * D / 8) + j * 512 + row] = word;
    if (j == 0) qsc[which * D + row] = m / 7.f;
}

// ---- K0b: per-row int8 quantization of Wo (50000 x 512), 4 rows/block ----
__global__ __launch_bounds__(256) void k_quant_wo(
        const float* __restrict__ Wo, int8_t* __restrict__ woq,
        float* __restrict__ wosc) {
    int row = blockIdx.x * 4 + (threadIdx.x >> 6);
    if (row >= EVOC) return;
    int lane = threadIdx.x & 63;
    const float4* src = (const float4*)(Wo + (size_t)row * D);
    float4 v0 = src[lane];
    float4 v1 = src[lane + 64];
    float m = fmaxf(fmaxf(fmaxf(fabsf(v0.x), fabsf(v0.y)), fmaxf(fabsf(v0.z), fabsf(v0.w))),
                    fmaxf(fmaxf(fabsf(v1.x), fabsf(v1.y)), fmaxf(fabsf(v1.z), fabsf(v1.w))));
    for (int off = 32; off; off >>= 1) m = fmaxf(m, __shfl_xor(m, off));
    float inv = (m > 0.f) ? 127.f / m : 0.f;
    uint32_t* dst = (uint32_t*)(woq + (size_t)row * D);
    dst[lane]      = pack4(v0.x, v0.y, v0.z, v0.w, inv);
    dst[lane + 64] = pack4(v1.x, v1.y, v1.z, v1.w, inv);
    if (lane == 0) wosc[row] = m / 127.f;
}

// ---- K1: pre[s][o] = emb[idx[s]] . Wih[o,:] + b[o]   (both enc & dec) ----
__global__ __launch_bounds__(256) void k_pre(
        const int* __restrict__ fnums, const int* __restrict__ enums,
        const float* __restrict__ emb_f, const float* __restrict__ emb_d,
        const float* __restrict__ Wih_e, const float* __restrict__ Wih_d,
        const float* __restrict__ b_e, const float* __restrict__ b_d,
        float* __restrict__ pre_e, float* __restrict__ pre_d) {
    __shared__ float xl[D];
    int bb = blockIdx.x;            // 0..255 : 128 enc + 128 dec
    int kind = bb >> 7, s = bb & 127;
    const float* emb = kind ? emb_d : emb_f;
    int idx          = kind ? enums[s] : fnums[s];
    const float* W   = kind ? Wih_d : Wih_e;
    const float* b   = kind ? b_d : b_e;
    float* pre       = kind ? pre_d : pre_e;
    int t = threadIdx.x;
    xl[t]       = emb[(size_t)idx * D + t];
    xl[t + 256] = emb[(size_t)idx * D + t + 256];
    __syncthreads();
    for (int rep = 0; rep < 2; rep++) {
        int o = t + rep * 256;
        float acc = b[o];
        const float4* Wr = (const float4*)(W + (size_t)o * D);
        #pragma unroll 8
        for (int k4 = 0; k4 < D / 4; k4++) {
            float4 w = Wr[k4];
            acc += w.x * xl[4*k4] + w.y * xl[4*k4+1] + w.z * xl[4*k4+2] + w.w * xl[4*k4+3];
        }
        pre[(size_t)s * D + o] = acc;
    }
}

// ---- K2: the two sequential scans. int4 weights LDS-RESIDENT (128 KB). ----
// Rounds 5-8: compiler refused register residency (4 variants, all VGPR=44,
// 183us = per-CU L2-BW roofline streaming 256KB/step). LDS is allocator-proof:
// int4 matrix = 128KB fits (160KB/CU). Layout [w][r]: ds_read_b32 bank = r%32,
// conflict-free; all 32 word offsets are compile-time ds immediates.
__global__ __launch_bounds__(1024) void k_scan(
        const uint32_t* __restrict__ q4, const float* __restrict__ qsc,
        const float* __restrict__ pre_e, const float* __restrict__ pre_d,
        const float* __restrict__ h0_e, const float* __restrict__ h0_d,
        float* __restrict__ fencs, float* __restrict__ h2s) {
    __shared__ uint32_t wlds[D * D / 8];               // 32768 u32 = 128 KB
    __shared__ __align__(16) uint32_t hq32[2][D / 4];  // int8 h, double-buffered
    int t = threadIdx.x;
    int r = t >> 1, hf = t & 1;
    int which = blockIdx.x;
    const uint32_t* q4g = q4 + (size_t)which * (D * D / 8);
    const float*  pre = which ? pre_d : pre_e;
    const float*  h0  = which ? h0_d : h0_e;
    float*        hs  = which ? h2s : fencs;

    // stage weights global->LDS (one-time, b128 both sides)
    {
        const u32x4* gq = (const u32x4*)q4g;
        u32x4* lq = (u32x4*)wlds;
        #pragma unroll
        for (int k = 0; k < 8; k++)
            lq[t + k * 1024] = gq[t + k * 1024];
    }

    int8_t* hq8 = (int8_t*)hq32;
    if (hf == 0) {
        float h0v = fminf(fmaxf(h0[r], -0.999f), 0.999f);
        hq8[r] = (int8_t)__float2int_rn(h0v * 127.f);
    }
    float sw = qsc[which * D + r] * (1.f / 127.f);
    __syncthreads();

    int p = 0;
    for (int step = 0; step < NSTEP; step++) {
        float prev = pre[(size_t)step * D + r];        // lane-pair broadcast
        const u32x4* hv = (const u32x4*)(&hq32[p][hf * 64]);
        const uint32_t* wbase = wlds + hf * 32 * 512 + r;
        int a0 = 0, a1 = 0;
        #pragma unroll
        for (int ii = 0; ii < 16; ii++) {
            u32x4 hh = hv[ii];                         // h cols 16ii..16ii+15 (of half)
            uint32_t wa = wbase[(2 * ii) * 512];       // cols 16ii..16ii+7
            uint32_t wb = wbase[(2 * ii + 1) * 512];   // cols 16ii+8..16ii+15
            a0 = sdot4((int)((wa << 4) & 0xF0F0F0F0u), (int)hh.x, a0);
            a1 = sdot4((int)( wa       & 0xF0F0F0F0u), (int)hh.y, a1);
            a0 = sdot4((int)((wb << 4) & 0xF0F0F0F0u), (int)hh.z, a0);
            a1 = sdot4((int)( wb       & 0xF0F0F0F0u), (int)hh.w, a1);
        }
        int acc = a0 + a1;
        acc += __shfl_xor(acc, 1);                     // combine half-rows
        acc >>= 4;                                     // exact: every term is q*16*h
        if (hf == 0) {
            float h2 = tanhf(prev + (float)acc * sw);
            hs[(size_t)step * D + r] = h2;
            hq8[(p ^ 1) * D + r] = (int8_t)__float2int_rn(h2 * 127.f);
        }
        p ^= 1;
        __syncthreads();
    }
}

// ---- K3: per decoder step: attention + m = tanh([c,h2] @ Wm^T + bm) -> int8 ----
// 512 threads (2 waves/SIMD); c-phase reads fencs via coalesced LDS tile
// staging instead of stride-2KB scattered global reads.
__global__ __launch_bounds__(512) void k_att(
        const float* __restrict__ fencs, const float* __restrict__ h2s,
        const float* __restrict__ Wm, const float* __restrict__ bm,
        int8_t* __restrict__ mq) {
    __shared__ float h2l[D], cl[D], sc[NSTEP], red[64];
    __shared__ float ftile[32 * D];     // 64 KB staged fencs tile
    int s = blockIdx.x, t = threadIdx.x;
    h2l[t] = h2s[(size_t)s * D + t];
    __syncthreads();

    {   // scores[j] = fencs[j] . h2 ; thread (j = t>>2, q = t&3)
        int j = t >> 2, q = t & 3;
        const float4* fr = (const float4*)(fencs + (size_t)j * D + q * 128);
        const float4* hr = (const float4*)(h2l + q * 128);
        float acc = 0.f;
        #pragma unroll 8
        for (int k4 = 0; k4 < 32; k4++) {
            float4 f = fr[k4], hh = hr[k4];
            acc += f.x*hh.x + f.y*hh.y + f.z*hh.z + f.w*hh.w;
        }
        acc += __shfl_xor(acc, 1);
        acc += __shfl_xor(acc, 2);
        if (q == 0) sc[j] = acc;
    }
    __syncthreads();
    if (t < 64) {
        float m = fmaxf(sc[t], sc[t + 64]);
        for (int off = 32; off; off >>= 1) m = fmaxf(m, __shfl_xor(m, off));
        if (t == 0) red[0] = m;
    }
    __syncthreads();
    float mx = red[0];
    __syncthreads();
    if (t < NSTEP) sc[t] = expf(sc[t] - mx);
    __syncthreads();
    if (t < 64) {
        float v = sc[t] + sc[t + 64];
        for (int off = 32; off; off >>= 1) v += __shfl_xor(v, off);
        if (t == 0) red[0] = v;
    }
    __syncthreads();
    float inv = 1.0f / red[0];

    // c[k] = sum_j alpha[j]*fencs[j][k], via 4 staged 32-row tiles
    float cacc = 0.f;
    for (int jt = 0; jt < 4; jt++) {
        #pragma unroll
        for (int k = 0; k < 32; k++)
            ftile[t + k * D] = fencs[(size_t)jt * 32 * D + t + k * D];
        __syncthreads();
        #pragma unroll 8
        for (int j = 0; j < 32; j++)
            cacc += sc[jt * 32 + j] * ftile[j * D + t];   // bank = t%32, clean
        __syncthreads();
    }
    cl[t] = cacc * inv;
    __syncthreads();

    {   // m[o] = tanh(Wm[o,:512].c + Wm[o,512:].h2 + bm), o = t
        float acc = bm[t];
        const float4* wr = (const float4*)(Wm + (size_t)t * 2 * D);
        const float4* cr = (const float4*)cl;
        const float4* hr = (const float4*)h2l;
        #pragma unroll 4
        for (int k4 = 0; k4 < D / 4; k4++) {
            float4 w = wr[k4], c = cr[k4];
            acc += w.x*c.x + w.y*c.y + w.z*c.z + w.w*c.w;
        }
        #pragma unroll 4
        for (int k4 = 0; k4 < D / 4; k4++) {
            float4 w = wr[D/4 + k4], hh = hr[k4];
            acc += w.x*hh.x + w.y*hh.y + w.z*hh.z + w.w*hh.w;
        }
        mq[(size_t)s * D + t] = (int8_t)__float2int_rn(tanhf(acc) * 127.f);
    }
}

// ---- K4: int8 logits GEMM (128 steps x 128 vocab, K=512) + fused row max/sumexp ----
__global__ __launch_bounds__(512) void k_logits(
        const int8_t* __restrict__ mq, const int8_t* __restrict__ woq,
        const float* __restrict__ wosc, const float* __restrict__ bo,
        const int* __restrict__ enums,
        float* __restrict__ pmax, float* __restrict__ psum, float* __restrict__ pick) {
    __shared__ uint32_t a_s[128 * LDA_W];   // 18.4 KB
    __shared__ uint32_t b_s[32 * LDB_W];    // 16.5 KB
    int b = blockIdx.x, t = threadIdx.x;
    int v0 = b * VTILE;
    int ti = t >> 5, tj = t & 31;           // out: rows ti*8+i, cols tj+32*jj
    int lrow = t >> 3, lq = t & 7;          // staging: 64 rows/rep, 8 16B-quads/row
    int acc[8][4] = {};

    for (int kc = 0; kc < 4; kc++) {        // K chunks of 128 int8 (32 words)
        #pragma unroll
        for (int rep = 0; rep < 2; rep++) {
            int row = lrow + rep * 64;
            uint4 av = *(const uint4*)(mq + (size_t)row * D + kc * 128 + lq * 16);
            *(uint4*)&a_s[row * LDA_W + lq * 4] = av;
            int v = v0 + row;
            uint4 bv = (v < EVOC)
                ? *(const uint4*)(woq + (size_t)v * D + kc * 128 + lq * 16)
                : make_uint4(0u, 0u, 0u, 0u);
            b_s[(lq*4+0) * LDB_W + row] = bv.x;
            b_s[(lq*4+1) * LDB_W + row] = bv.y;
            b_s[(lq*4+2) * LDB_W + row] = bv.z;
            b_s[(lq*4+3) * LDB_W + row] = bv.w;
        }
        __syncthreads();
        #pragma unroll
        for (int q = 0; q < 8; q++) {
            uint4 aw[8];
            #pragma unroll
            for (int i = 0; i < 8; i++)
                aw[i] = *(const uint4*)&a_s[(ti*8 + i) * LDA_W + q*4];
            #pragma unroll
            for (int k4 = 0; k4 < 4; k4++) {
                uint32_t bw[4];
                #pragma unroll
                for (int jj = 0; jj < 4; jj++)
                    bw[jj] = b_s[(q*4 + k4) * LDB_W + tj + 32*jj];
                #pragma unroll
                for (int i = 0; i < 8; i++) {
                    uint32_t a = (k4 == 0) ? aw[i].x : (k4 == 1) ? aw[i].y
                               : (k4 == 2) ? aw[i].z : aw[i].w;
                    #pragma unroll
                    for (int jj = 0; jj < 4; jj++)
                        acc[i][jj] = sdot4((int)a, (int)bw[jj], acc[i][jj]);
                }
            }
        }
        __syncthreads();
    }

    float sw4[4], bo4[4];
    int vld[4];
    #pragma unroll
    for (int jj = 0; jj < 4; jj++) {
        int v = v0 + tj + 32*jj;
        vld[jj] = (v < EVOC);
        sw4[jj] = vld[jj] ? wosc[v] * (1.f/127.f) : 0.f;
        bo4[jj] = vld[jj] ? bo[v] : 0.f;
    }
    #pragma unroll
    for (int i = 0; i < 8; i++) {
        int s = ti * 8 + i;
        float l[4];
        float mx = -1e30f;
        #pragma unroll
        for (int jj = 0; jj < 4; jj++) {
            l[jj] = vld[jj] ? (float)acc[i][jj] * sw4[jj] + bo4[jj] : -1e30f;
            mx = fmaxf(mx, l[jj]);
        }
        #pragma unroll
        for (int off = 1; off < 32; off <<= 1) mx = fmaxf(mx, __shfl_xor(mx, off));
        float sm = 0.f;
        #pragma unroll
        for (int jj = 0; jj < 4; jj++)
            if (vld[jj]) sm += expf(l[jj] - mx);
        #pragma unroll
        for (int off = 1; off < 32; off <<= 1) sm += __shfl_xor(sm, off);
        if (tj == 0) { pmax[b * NSTEP + s] = mx; psum[b * NSTEP + s] = sm; }
        int tgt = enums[s + 1];
        if (tgt >= v0 && tgt < v0 + VTILE) {
            int c = tgt - v0;
            if ((c & 31) == tj) pick[s] = l[c >> 5];
        }
    }
}

// ---- K5: combine partial logsumexps, pick target logprobs, sum ----
__global__ void k_final(const float* __restrict__ pmax, const float* __restrict__ psum,
                        const float* __restrict__ pick, float* __restrict__ out) {
    __shared__ float red[NSTEP];
    int t = threadIdx.x;     // 128 threads, one per decoder step
    float M = -1e30f;
    for (int b = 0; b < NBV; b++) M = fmaxf(M, pmax[b * NSTEP + t]);
    float S = 0.f;
    for (int b = 0; b < NBV; b++) S += psum[b * NSTEP + t] * expf(pmax[b * NSTEP + t] - M);
    red[t] = pick[t] - (M + logf(S));
    __syncthreads();
    for (int off = 64; off > 0; off >>= 1) {
        if (t < off) red[t] += red[t + off];
        __syncthreads();
    }
    if (t == 0) out[0] = red[0];
}

extern "C" void kernel_launch(void* const* d_in, const int* in_sizes, int n_in,
                              void* d_out, int out_size, void* d_ws, size_t ws_size,
                              hipStream_t stream) {
    const int*   fnums = (const int*)  d_in[0];
    const int*   enums = (const int*)  d_in[1];
    const float* emb_f = (const float*)d_in[2];
    const float* Wih_e = (const float*)d_in[3];
    const float* Whh_e = (const float*)d_in[4];
    const float* b_e   = (const float*)d_in[5];
    const float* h0_e  = (const float*)d_in[6];
    const float* emb_d = (const float*)d_in[7];
    const float* Wih_d = (const float*)d_in[8];
    const float* Whh_d = (const float*)d_in[9];
    const float* b_d   = (const float*)d_in[10];
    const float* h0_d  = (const float*)d_in[11];
    const float* Wm    = (const float*)d_in[12];
    const float* bm    = (const float*)d_in[13];
    const float* Wo    = (const float*)d_in[14];
    const float* bo    = (const float*)d_in[15];

    float* ws = (float*)d_ws;
    float* pre_e = ws;                       // 65536
    float* pre_d = ws + 65536;               // 65536
    float* fencs = ws + 131072;              // 65536
    float* h2s   = ws + 196608;              // 65536
    float* pmax  = ws + 262144;              // 50048
    float* psum  = ws + 312192;              // 50048
    float* pick  = ws + 362240;              // 128
    float* qsc   = ws + 362368;              // 1024
    uint32_t* q4 = (uint32_t*)(ws + 363392); // 65536 u32 = 256 KB int4 scan weights
    float* wosc  = ws + 428928;              // 50048
    int8_t* mq   = (int8_t*)(ws + 478976);   // 64 KB
    int8_t* woq  = (int8_t*)(ws + 495360);   // 25.6 MB

    k_quant<<<dim3(1024), dim3(64), 0, stream>>>(Whh_e, Whh_d, q4, qsc);
    k_quant_wo<<<dim3((EVOC + 3) / 4), dim3(256), 0, stream>>>(Wo, woq, wosc);
    k_pre<<<dim3(256), dim3(256), 0, stream>>>(fnums, enums, emb_f, emb_d,
                                               Wih_e, Wih_d, b_e, b_d, pre_e, pre_d);
    k_scan<<<dim3(2), dim3(1024), 0, stream>>>(q4, qsc, pre_e, pre_d, h0_e, h0_d, fencs, h2s);
    k_att<<<dim3(NSTEP), dim3(512), 0, stream>>>(fencs, h2s, Wm, bm, mq);
    k_logits<<<dim3(NBV), dim3(512), 0, stream>>>(mq, woq, wosc, bo, enums, pmax, psum, pick);
    k_final<<<dim3(1), dim3(NSTEP), 0, stream>>>(pmax, psum, pick, (float*)d_out);
}

// Round 10
// 511.957 us; speedup vs baseline: 1.0817x; 1.0817x over previous
//
#include <hip/hip_runtime.h>
#include <stdint.h>

#define D      512
#define NSTEP  128          // SRC steps == decoder steps (TGT-1)
#define EVOC   50000
#define VTILE  128
#define NBV    ((EVOC + VTILE - 1) / VTILE)   // 391
#define LDA_W  36           // A LDS row stride in u32 words (144 B, 16B-aligned)
#define LDB_W  129          // B LDS kw-row stride in u32 words (128 cols + 1 pad)

typedef unsigned int u32x4 __attribute__((ext_vector_type(4)));

// ---- int8 dot4 (v_dot4_i32_i8) ----
__device__ inline int sdot4(int a, int b, int c) {
#if __has_builtin(__builtin_amdgcn_sdot4)
    return __builtin_amdgcn_sdot4(a, b, c, false);
#else
    int r = c;
    r += (int)(int8_t)(a)       * (int)(int8_t)(b);
    r += (int)(int8_t)(a >> 8)  * (int)(int8_t)(b >> 8);
    r += (int)(int8_t)(a >> 16) * (int)(int8_t)(b >> 16);
    r += (int)(int8_t)(a >> 24) * (int)(int8_t)(b >> 24);
    return r;
#endif
}

__device__ inline uint32_t pack4(float a, float b, float c, float d, float inv) {
    return  ((uint32_t)(uint8_t)(int8_t)__float2int_rn(a * inv)) |
            ((uint32_t)(uint8_t)(int8_t)__float2int_rn(b * inv) << 8) |
            ((uint32_t)(uint8_t)(int8_t)__float2int_rn(c * inv) << 16) |
            ((uint32_t)(uint8_t)(int8_t)__float2int_rn(d * inv) << 24);
}

// ---- K0: per-row symmetric INT4 quantization of Whh_e / Whh_d ----
// Nibble packing per word (8 cols): byte b = (q[8m+b]&0xF) | (q[8m+b+4]&0xF)<<4:
//   ((x<<4)&0xF0F0F0F0) = bytes q[8m+0..3]*16 (signed exact)
//   ( x    &0xF0F0F0F0) = bytes q[8m+4..7]*16
// Consumer sdot4-accumulates, one exact >>4 at the end (round-9 math, absmax 0.0).
// NEW LAYOUT: u32x4 chunk index = which*8192 + c*1024 + t, where t = 2*row + (j>>5)
// is the consumer thread and c = (j&31)>>2 its chunk -> k_scan's 8 global b128
// loads per lane are perfectly coalesced (64 consecutive 16B chunks per wave).
__global__ __launch_bounds__(64) void k_quant(
        const float* __restrict__ We, const float* __restrict__ Wd,
        uint32_t* __restrict__ q4, float* __restrict__ qsc) {
    int bid = blockIdx.x;                 // 0..1023
    int which = bid >> 9, row = bid & 511;
    const float* W = which ? Wd : We;
    int j = threadIdx.x;                  // word index 0..63, cols 8j..8j+7
    const float* src = W + (size_t)row * D + j * 8;
    float w[8];
    #pragma unroll
    for (int k = 0; k < 8; k++) w[k] = src[k];
    float m = 0.f;
    #pragma unroll
    for (int k = 0; k < 8; k++) m = fmaxf(m, fabsf(w[k]));
    for (int off = 32; off; off >>= 1) m = fmaxf(m, __shfl_xor(m, off));
    float inv = (m > 0.f) ? 7.f / m : 0.f;
    uint32_t word = 0;
    #pragma unroll
    for (int b = 0; b < 4; b++) {
        int qlo = __float2int_rn(w[b] * inv);
        int qhi = __float2int_rn(w[b + 4] * inv);
        qlo = max(-7, min(7, qlo));
        qhi = max(-7, min(7, qhi));
        word |= (((uint32_t)(qlo & 0xF)) | ((uint32_t)(qhi & 0xF) << 4)) << (8 * b);
    }
    int hf = j >> 5, mm = j & 31;
    int c = mm >> 2, wic = mm & 3;
    int t = row * 2 + hf;
    q4[(size_t)which * 32768 + ((size_t)c * 1024 + t) * 4 + wic] = word;
    if (j == 0) qsc[which * D + row] = m / 7.f;
}

// ---- K0b: per-row int8 quantization of Wo (50000 x 512), 4 rows/block ----
__global__ __launch_bounds__(256) void k_quant_wo(
        const float* __restrict__ Wo, int8_t* __restrict__ woq,
        float* __restrict__ wosc) {
    int row = blockIdx.x * 4 + (threadIdx.x >> 6);
    if (row >= EVOC) return;
    int lane = threadIdx.x & 63;
    const float4* src = (const float4*)(Wo + (size_t)row * D);
    float4 v0 = src[lane];
    float4 v1 = src[lane + 64];
    float m = fmaxf(fmaxf(fmaxf(fabsf(v0.x), fabsf(v0.y)), fmaxf(fabsf(v0.z), fabsf(v0.w))),
                    fmaxf(fmaxf(fabsf(v1.x), fabsf(v1.y)), fmaxf(fabsf(v1.z), fabsf(v1.w))));
    for (int off = 32; off; off >>= 1) m = fmaxf(m, __shfl_xor(m, off));
    float inv = (m > 0.f) ? 127.f / m : 0.f;
    uint32_t* dst = (uint32_t*)(woq + (size_t)row * D);
    dst[lane]      = pack4(v0.x, v0.y, v0.z, v0.w, inv);
    dst[lane + 64] = pack4(v1.x, v1.y, v1.z, v1.w, inv);
    if (lane == 0) wosc[row] = m / 127.f;
}

// ---- K1: pre[s][o] = emb[idx[s]] . Wih[o,:] + b[o]   (both enc & dec) ----
__global__ __launch_bounds__(256) void k_pre(
        const int* __restrict__ fnums, const int* __restrict__ enums,
        const float* __restrict__ emb_f, const float* __restrict__ emb_d,
        const float* __restrict__ Wih_e, const float* __restrict__ Wih_d,
        const float* __restrict__ b_e, const float* __restrict__ b_d,
        float* __restrict__ pre_e, float* __restrict__ pre_d) {
    __shared__ float xl[D];
    int bb = blockIdx.x;            // 0..255 : 128 enc + 128 dec
    int kind = bb >> 7, s = bb & 127;
    const float* emb = kind ? emb_d : emb_f;
    int idx          = kind ? enums[s] : fnums[s];
    const float* W   = kind ? Wih_d : Wih_e;
    const float* b   = kind ? b_d : b_e;
    float* pre       = kind ? pre_d : pre_e;
    int t = threadIdx.x;
    xl[t]       = emb[(size_t)idx * D + t];
    xl[t + 256] = emb[(size_t)idx * D + t + 256];
    __syncthreads();
    for (int rep = 0; rep < 2; rep++) {
        int o = t + rep * 256;
        float acc = b[o];
        const float4* Wr = (const float4*)(W + (size_t)o * D);
        #pragma unroll 8
        for (int k4 = 0; k4 < D / 4; k4++) {
            float4 w = Wr[k4];
            acc += w.x * xl[4*k4] + w.y * xl[4*k4+1] + w.z * xl[4*k4+2] + w.w * xl[4*k4+3];
        }
        pre[(size_t)s * D + o] = acc;
    }
}

// ---- K2: the two sequential scans. int4 weights STREAMED FROM L2 each step. ----
// Round-5 evidence: the compiler's sunk-loads version streamed 256KB(int8)/step
// from L2 at ~75 B/cyc/CU = 3430 cyc/step (183us) -- pure L2-BW-bound. int4
// halves the bytes -> ~1700 cyc/step on the VMEM pipe, OVERLAPPING the h-reads
// on the LDS pipe (~1000-1500 cyc). Round-9's mistake: both streams on the LDS
// pipe + 32 scalar b32/lane (289us). The asm-redefined `zero` inside the loop
// makes the addresses non-loop-invariant: loads can't be hoisted-then-spilled.
__global__ __launch_bounds__(1024) void k_scan(
        const uint32_t* __restrict__ q4, const float* __restrict__ qsc,
        const float* __restrict__ pre_e, const float* __restrict__ pre_d,
        const float* __restrict__ h0_e, const float* __restrict__ h0_d,
        float* __restrict__ fencs, float* __restrict__ h2s) {
    __shared__ __align__(16) uint32_t hq32[2][D / 4];  // int8 h, double-buffered
    int t = threadIdx.x;
    int r = t >> 1, hf = t & 1;
    int which = blockIdx.x;
    const u32x4* wg = (const u32x4*)q4 + (size_t)which * 8192 + t;
    const float* pre = which ? pre_d : pre_e;
    const float* h0  = which ? h0_d : h0_e;
    float*       hs  = which ? h2s : fencs;

    int8_t* hq8 = (int8_t*)hq32;
    if (hf == 0) {
        float h0v = fminf(fmaxf(h0[r], -0.999f), 0.999f);
        hq8[r] = (int8_t)__float2int_rn(h0v * 127.f);
    }
    float sw = qsc[which * D + r] * (1.f / 127.f);
    __syncthreads();

    const uint32_t M = 0xF0F0F0F0u;
    int zero = 0;
    int p = 0;
    for (int step = 0; step < NSTEP; step++) {
        asm volatile("" : "+v"(zero));             // defeat load hoisting/spill
        float prev = pre[(size_t)step * D + r];    // lane-pair broadcast, L2-hot
        const u32x4* hv = (const u32x4*)(&hq32[p][hf * 64]);
        int a0 = 0, a1 = 0;
        #pragma unroll
        for (int c = 0; c < 8; c++) {
            u32x4 wv = wg[c * 1024 + zero];        // coalesced 16B/lane from L2
            u32x4 ha = hv[2 * c];                  // h words 8c..8c+3 (broadcast)
            u32x4 hb = hv[2 * c + 1];              // h words 8c+4..8c+7
            a0 = sdot4((int)((wv.x << 4) & M), (int)ha.x, a0);
            a1 = sdot4((int)( wv.x       & M), (int)ha.y, a1);
            a0 = sdot4((int)((wv.y << 4) & M), (int)ha.z, a0);
            a1 = sdot4((int)( wv.y       & M), (int)ha.w, a1);
            a0 = sdot4((int)((wv.z << 4) & M), (int)hb.x, a0);
            a1 = sdot4((int)( wv.z       & M), (int)hb.y, a1);
            a0 = sdot4((int)((wv.w << 4) & M), (int)hb.z, a0);
            a1 = sdot4((int)( wv.w       & M), (int)hb.w, a1);
        }
        int acc = a0 + a1;
        acc += __shfl_xor(acc, 1);                 // combine the two half-rows
        acc >>= 4;                                 // exact: every term is q*16*h
        if (hf == 0) {
            float h2 = tanhf(prev + (float)acc * sw);
            hs[(size_t)step * D + r] = h2;
            hq8[(p ^ 1) * D + r] = (int8_t)__float2int_rn(h2 * 127.f);
        }
        p ^= 1;
        __syncthreads();
    }
}

// ---- K3: per decoder step: attention + m = tanh([c,h2] @ Wm^T + bm) -> int8 ----
__global__ __launch_bounds__(512) void k_att(
        const float* __restrict__ fencs, const float* __restrict__ h2s,
        const float* __restrict__ Wm, const float* __restrict__ bm,
        int8_t* __restrict__ mq) {
    __shared__ float h2l[D], cl[D], sc[NSTEP], red[64];
    __shared__ float ftile[32 * D];     // 64 KB staged fencs tile
    int s = blockIdx.x, t = threadIdx.x;
    h2l[t] = h2s[(size_t)s * D + t];
    __syncthreads();

    {   // scores[j] = fencs[j] . h2 ; thread (j = t>>2, q = t&3)
        int j = t >> 2, q = t & 3;
        const float4* fr = (const float4*)(fencs + (size_t)j * D + q * 128);
        const float4* hr = (const float4*)(h2l + q * 128);
        float acc = 0.f;
        #pragma unroll 8
        for (int k4 = 0; k4 < 32; k4++) {
            float4 f = fr[k4], hh = hr[k4];
            acc += f.x*hh.x + f.y*hh.y + f.z*hh.z + f.w*hh.w;
        }
        acc += __shfl_xor(acc, 1);
        acc += __shfl_xor(acc, 2);
        if (q == 0) sc[j] = acc;
    }
    __syncthreads();
    if (t < 64) {
        float m = fmaxf(sc[t], sc[t + 64]);
        for (int off = 32; off; off >>= 1) m = fmaxf(m, __shfl_xor(m, off));
        if (t == 0) red[0] = m;
    }
    __syncthreads();
    float mx = red[0];
    __syncthreads();
    if (t < NSTEP) sc[t] = expf(sc[t] - mx);
    __syncthreads();
    if (t < 64) {
        float v = sc[t] + sc[t + 64];
        for (int off = 32; off; off >>= 1) v += __shfl_xor(v, off);
        if (t == 0) red[0] = v;
    }
    __syncthreads();
    float inv = 1.0f / red[0];

    // c[k] = sum_j alpha[j]*fencs[j][k], via 4 staged 32-row tiles
    float cacc = 0.f;
    for (int jt = 0; jt < 4; jt++) {
        #pragma unroll
        for (int k = 0; k < 32; k++)
            ftile[t + k * D] = fencs[(size_t)jt * 32 * D + t + k * D];
        __syncthreads();
        #pragma unroll 8
        for (int j = 0; j < 32; j++)
            cacc += sc[jt * 32 + j] * ftile[j * D + t];   // bank = t%32, clean
        __syncthreads();
    }
    cl[t] = cacc * inv;
    __syncthreads();

    {   // m[o] = tanh(Wm[o,:512].c + Wm[o,512:].h2 + bm), o = t
        float acc = bm[t];
        const float4* wr = (const float4*)(Wm + (size_t)t * 2 * D);
        const float4* cr = (const float4*)cl;
        const float4* hr = (const float4*)h2l;
        #pragma unroll 4
        for (int k4 = 0; k4 < D / 4; k4++) {
            float4 w = wr[k4], c = cr[k4];
            acc += w.x*c.x + w.y*c.y + w.z*c.z + w.w*c.w;
        }
        #pragma unroll 4
        for (int k4 = 0; k4 < D / 4; k4++) {
            float4 w = wr[D/4 + k4], hh = hr[k4];
            acc += w.x*hh.x + w.y*hh.y + w.z*hh.z + w.w*hh.w;
        }
        mq[(size_t)s * D + t] = (int8_t)__float2int_rn(tanhf(acc) * 127.f);
    }
}

// ---- K4: int8 logits GEMM (128 steps x 128 vocab, K=512) + fused row max/sumexp ----
__global__ __launch_bounds__(512) void k_logits(
        const int8_t* __restrict__ mq, const int8_t* __restrict__ woq,
        const float* __restrict__ wosc, const float* __restrict__ bo,
        const int* __restrict__ enums,
        float* __restrict__ pmax, float* __restrict__ psum, float* __restrict__ pick) {
    __shared__ uint32_t a_s[128 * LDA_W];   // 18.4 KB
    __shared__ uint32_t b_s[32 * LDB_W];    // 16.5 KB
    int b = blockIdx.x, t = threadIdx.x;
    int v0 = b * VTILE;
    int ti = t >> 5, tj = t & 31;           // out: rows ti*8+i, cols tj+32*jj
    int lrow = t >> 3, lq = t & 7;          // staging: 64 rows/rep, 8 16B-quads/row
    int acc[8][4] = {};

    for (int kc = 0; kc < 4; kc++) {        // K chunks of 128 int8 (32 words)
        #pragma unroll
        for (int rep = 0; rep < 2; rep++) {
            int row = lrow + rep * 64;
            uint4 av = *(const uint4*)(mq + (size_t)row * D + kc * 128 + lq * 16);
            *(uint4*)&a_s[row * LDA_W + lq * 4] = av;
            int v = v0 + row;
            uint4 bv = (v < EVOC)
                ? *(const uint4*)(woq + (size_t)v * D + kc * 128 + lq * 16)
                : make_uint4(0u, 0u, 0u, 0u);
            b_s[(lq*4+0) * LDB_W + row] = bv.x;
            b_s[(lq*4+1) * LDB_W + row] = bv.y;
            b_s[(lq*4+2) * LDB_W + row] = bv.z;
            b_s[(lq*4+3) * LDB_W + row] = bv.w;
        }
        __syncthreads();
        #pragma unroll
        for (int q = 0; q < 8; q++) {
            uint4 aw[8];
            #pragma unroll
            for (int i = 0; i < 8; i++)
                aw[i] = *(const uint4*)&a_s[(ti*8 + i) * LDA_W + q*4];
            #pragma unroll
            for (int k4 = 0; k4 < 4; k4++) {
                uint32_t bw[4];
                #pragma unroll
                for (int jj = 0; jj < 4; jj++)
                    bw[jj] = b_s[(q*4 + k4) * LDB_W + tj + 32*jj];
                #pragma unroll
                for (int i = 0; i < 8; i++) {
                    uint32_t a = (k4 == 0) ? aw[i].x : (k4 == 1) ? aw[i].y
                               : (k4 == 2) ? aw[i].z : aw[i].w;
                    #pragma unroll
                    for (int jj = 0; jj < 4; jj++)
                        acc[i][jj] = sdot4((int)a, (int)bw[jj], acc[i][jj]);
                }
            }
        }
        __syncthreads();
    }

    float sw4[4], bo4[4];
    int vld[4];
    #pragma unroll
    for (int jj = 0; jj < 4; jj++) {
        int v = v0 + tj + 32*jj;
        vld[jj] = (v < EVOC);
        sw4[jj] = vld[jj] ? wosc[v] * (1.f/127.f) : 0.f;
        bo4[jj] = vld[jj] ? bo[v] : 0.f;
    }
    #pragma unroll
    for (int i = 0; i < 8; i++) {
        int s = ti * 8 + i;
        float l[4];
        float mx = -1e30f;
        #pragma unroll
        for (int jj = 0; jj < 4; jj++) {
            l[jj] = vld[jj] ? (float)acc[i][jj] * sw4[jj] + bo4[jj] : -1e30f;
            mx = fmaxf(mx, l[jj]);
        }
        #pragma unroll
        for (int off = 1; off < 32; off <<= 1) mx = fmaxf(mx, __shfl_xor(mx, off));
        float sm = 0.f;
        #pragma unroll
        for (int jj = 0; jj < 4; jj++)
            if (vld[jj]) sm += expf(l[jj] - mx);
        #pragma unroll
        for (int off = 1; off < 32; off <<= 1) sm += __shfl_xor(sm, off);
        if (tj == 0) { pmax[b * NSTEP + s] = mx; psum[b * NSTEP + s] = sm; }
        int tgt = enums[s + 1];
        if (tgt >= v0 && tgt < v0 + VTILE) {
            int c = tgt - v0;
            if ((c & 31) == tj) pick[s] = l[c >> 5];
        }
    }
}

// ---- K5: combine partial logsumexps, pick target logprobs, sum ----
__global__ void k_final(const float* __restrict__ pmax, const float* __restrict__ psum,
                        const float* __restrict__ pick, float* __restrict__ out) {
    __shared__ float red[NSTEP];
    int t = threadIdx.x;     // 128 threads, one per decoder step
    float M = -1e30f;
    for (int b = 0; b < NBV; b++) M = fmaxf(M, pmax[b * NSTEP + t]);
    float S = 0.f;
    for (int b = 0; b < NBV; b++) S += psum[b * NSTEP + t] * expf(pmax[b * NSTEP + t] - M);
    red[t] = pick[t] - (M + logf(S));
    __syncthreads();
    for (int off = 64; off > 0; off >>= 1) {
        if (t < off) red[t] += red[t + off];
        __syncthreads();
    }
    if (t == 0) out[0] = red[0];
}

extern "C" void kernel_launch(void* const* d_in, const int* in_sizes, int n_in,
                              void* d_out, int out_size, void* d_ws, size_t ws_size,
                              hipStream_t stream) {
    const int*   fnums = (const int*)  d_in[0];
    const int*   enums = (const int*)  d_in[1];
    const float* emb_f = (const float*)d_in[2];
    const float* Wih_e = (const float*)d_in[3];
    const float* Whh_e = (const float*)d_in[4];
    const float* b_e   = (const float*)d_in[5];
    const float* h0_e  = (const float*)d_in[6];
    const float* emb_d = (const float*)d_in[7];
    const float* Wih_d = (const float*)d_in[8];
    const float* Whh_d = (const float*)d_in[9];
    const float* b_d   = (const float*)d_in[10];
    const float* h0_d  = (const float*)d_in[11];
    const float* Wm    = (const float*)d_in[12];
    const float* bm    = (const float*)d_in[13];
    const float* Wo    = (const float*)d_in[14];
    const float* bo    = (const float*)d_in[15];

    float* ws = (float*)d_ws;
    float* pre_e = ws;                       // 65536
    float* pre_d = ws + 65536;               // 65536
    float* fencs = ws + 131072;              // 65536
    float* h2s   = ws + 196608;              // 65536
    float* pmax  = ws + 262144;              // 50048
    float* psum  = ws + 312192;              // 50048
    float* pick  = ws + 362240;              // 128
    float* qsc   = ws + 362368;              // 1024
    uint32_t* q4 = (uint32_t*)(ws + 363392); // 65536 u32 = 256 KB int4 scan weights
    float* wosc  = ws + 428928;              // 50048
    int8_t* mq   = (int8_t*)(ws + 478976);   // 64 KB
    int8_t* woq  = (int8_t*)(ws + 495360);   // 25.6 MB

    k_quant<<<dim3(1024), dim3(64), 0, stream>>>(Whh_e, Whh_d, q4, qsc);
    k_quant_wo<<<dim3((EVOC + 3) / 4), dim3(256), 0, stream>>>(Wo, woq, wosc);
    k_pre<<<dim3(256), dim3(256), 0, stream>>>(fnums, enums, emb_f, emb_d,
                                               Wih_e, Wih_d, b_e, b_d, pre_e, pre_d);
    k_scan<<<dim3(2), dim3(1024), 0, stream>>>(q4, qsc, pre_e, pre_d, h0_e, h0_d, fencs, h2s);
    k_att<<<dim3(NSTEP), dim3(512), 0, stream>>>(fencs, h2s, Wm, bm, mq);
    k_logits<<<dim3(NBV), dim3(512), 0, stream>>>(mq, woq, wosc, bo, enums, pmax, psum, pick);
    k_final<<<dim3(1), dim3(NSTEP), 0, stream>>>(pmax, psum, pick, (float*)d_out);
}

// Round 11
// 448.346 us; speedup vs baseline: 1.2352x; 1.1419x over previous
//
#include <hip/hip_runtime.h>
#include <stdint.h>

#define D      512
#define NSTEP  128          // SRC steps == decoder steps (TGT-1)
#define EVOC   50000
#define VTILE  128
#define NBV    ((EVOC + VTILE - 1) / VTILE)   // 391
#define LDA_W  36           // A LDS row stride in u32 words (144 B, 16B-aligned)
#define LDB_W  129          // B LDS kw-row stride in u32 words (128 cols + 1 pad)

typedef unsigned int u32x4 __attribute__((ext_vector_type(4)));

// ---- int8 dot4 (v_dot4_i32_i8) ----
__device__ inline int sdot4(int a, int b, int c) {
#if __has_builtin(__builtin_amdgcn_sdot4)
    return __builtin_amdgcn_sdot4(a, b, c, false);
#else
    int r = c;
    r += (int)(int8_t)(a)       * (int)(int8_t)(b);
    r += (int)(int8_t)(a >> 8)  * (int)(int8_t)(b >> 8);
    r += (int)(int8_t)(a >> 16) * (int)(int8_t)(b >> 16);
    r += (int)(int8_t)(a >> 24) * (int)(int8_t)(b >> 24);
    return r;
#endif
}

__device__ inline uint32_t pack4(float a, float b, float c, float d, float inv) {
    return  ((uint32_t)(uint8_t)(int8_t)__float2int_rn(a * inv)) |
            ((uint32_t)(uint8_t)(int8_t)__float2int_rn(b * inv) << 8) |
            ((uint32_t)(uint8_t)(int8_t)__float2int_rn(c * inv) << 16) |
            ((uint32_t)(uint8_t)(int8_t)__float2int_rn(d * inv) << 24);
}

// ---- K0: per-row symmetric int8 quantization of Whh_e / Whh_d (row-major) ----
__global__ __launch_bounds__(64) void k_quant(
        const float* __restrict__ We, const float* __restrict__ Wd,
        int8_t* __restrict__ q8, float* __restrict__ qsc) {
    int bid = blockIdx.x;                 // 0..1023
    int which = bid >> 9, row = bid & 511;
    const float* W = which ? Wd : We;
    int lane = threadIdx.x;
    const float* src = W + (size_t)row * D + lane * 8;
    float4 v0 = ((const float4*)src)[0];
    float4 v1 = ((const float4*)src)[1];
    float m = fmaxf(fmaxf(fmaxf(fabsf(v0.x), fabsf(v0.y)), fmaxf(fabsf(v0.z), fabsf(v0.w))),
                    fmaxf(fmaxf(fabsf(v1.x), fabsf(v1.y)), fmaxf(fabsf(v1.z), fabsf(v1.w))));
    for (int off = 32; off; off >>= 1) m = fmaxf(m, __shfl_xor(m, off));
    float inv = (m > 0.f) ? 127.f / m : 0.f;
    uint32_t lo = pack4(v0.x, v0.y, v0.z, v0.w, inv);
    uint32_t hi = pack4(v1.x, v1.y, v1.z, v1.w, inv);
    uint2* dst = (uint2*)(q8 + (size_t)which * D * D + (size_t)row * D);
    dst[lane] = make_uint2(lo, hi);
    if (lane == 0) qsc[which * D + row] = m / 127.f;
}

// ---- K0b: per-row int8 quantization of Wo (50000 x 512), 4 rows/block ----
__global__ __launch_bounds__(256) void k_quant_wo(
        const float* __restrict__ Wo, int8_t* __restrict__ woq,
        float* __restrict__ wosc) {
    int row = blockIdx.x * 4 + (threadIdx.x >> 6);
    if (row >= EVOC) return;
    int lane = threadIdx.x & 63;
    const float4* src = (const float4*)(Wo + (size_t)row * D);
    float4 v0 = src[lane];
    float4 v1 = src[lane + 64];
    float m = fmaxf(fmaxf(fmaxf(fabsf(v0.x), fabsf(v0.y)), fmaxf(fabsf(v0.z), fabsf(v0.w))),
                    fmaxf(fmaxf(fabsf(v1.x), fabsf(v1.y)), fmaxf(fabsf(v1.z), fabsf(v1.w))));
    for (int off = 32; off; off >>= 1) m = fmaxf(m, __shfl_xor(m, off));
    float inv = (m > 0.f) ? 127.f / m : 0.f;
    uint32_t* dst = (uint32_t*)(woq + (size_t)row * D);
    dst[lane]      = pack4(v0.x, v0.y, v0.z, v0.w, inv);
    dst[lane + 64] = pack4(v1.x, v1.y, v1.z, v1.w, inv);
    if (lane == 0) wosc[row] = m / 127.f;
}

// ---- K1: pre[s][o] = emb[idx[s]] . Wih[o,:] + b[o]   (both enc & dec) ----
__global__ __launch_bounds__(256) void k_pre(
        const int* __restrict__ fnums, const int* __restrict__ enums,
        const float* __restrict__ emb_f, const float* __restrict__ emb_d,
        const float* __restrict__ Wih_e, const float* __restrict__ Wih_d,
        const float* __restrict__ b_e, const float* __restrict__ b_d,
        float* __restrict__ pre_e, float* __restrict__ pre_d) {
    __shared__ float xl[D];
    int bb = blockIdx.x;            // 0..255 : 128 enc + 128 dec
    int kind = bb >> 7, s = bb & 127;
    const float* emb = kind ? emb_d : emb_f;
    int idx          = kind ? enums[s] : fnums[s];
    const float* W   = kind ? Wih_d : Wih_e;
    const float* b   = kind ? b_d : b_e;
    float* pre       = kind ? pre_d : pre_e;
    int t = threadIdx.x;
    xl[t]       = emb[(size_t)idx * D + t];
    xl[t + 256] = emb[(size_t)idx * D + t + 256];
    __syncthreads();
    for (int rep = 0; rep < 2; rep++) {
        int o = t + rep * 256;
        float acc = b[o];
        const float4* Wr = (const float4*)(W + (size_t)o * D);
        #pragma unroll 8
        for (int k4 = 0; k4 < D / 4; k4++) {
            float4 w = Wr[k4];
            acc += w.x * xl[4*k4] + w.y * xl[4*k4+1] + w.z * xl[4*k4+2] + w.w * xl[4*k4+3];
        }
        pre[(size_t)s * D + o] = acc;
    }
}

// ---- K2: the two sequential scans, int8 x dot4, weights register-resident. ----
// Mechanism discovery (rounds 5-10): __launch_bounds__'s 2nd arg only sets the
// MIN of amdgpu-waves-per-eu; the allocator optimizes for the MAX (8-10/EU,
// ~44 VGPR) and sinks the weight loads into the loop (183us = L2-BW roofline
// of that stream). amdgpu_waves_per_eu(4,4) pins the hard MAX to 4/EU (= our
// one 16-wave block) -> 128-VGPR budget with no occupancy reward for fewer.
// The in-loop "+v" asm redefines the 16 weight quads every iteration, so they
// cannot be rematerialized from memory; the cheapest legal allocation is to
// keep them resident (~110 live regs <= 128).
__global__ __launch_bounds__(1024)
__attribute__((amdgpu_waves_per_eu(4, 4)))
void k_scan(
        const int8_t* __restrict__ q8, const float* __restrict__ qsc,
        const float* __restrict__ pre_e, const float* __restrict__ pre_d,
        const float* __restrict__ h0_e, const float* __restrict__ h0_d,
        float* __restrict__ fencs, float* __restrict__ h2s) {
    __shared__ __align__(16) int8_t hq[2][D];
    int t = threadIdx.x;
    int r = t >> 1, hf = t & 1;
    int which = blockIdx.x;
    const int8_t* w8 = q8 + (size_t)which * D * D;
    const float*  pre = which ? pre_d : pre_e;
    const float*  h0  = which ? h0_d : h0_e;
    float*        hs  = which ? h2s : fencs;
    float sw = qsc[which * D + r] * (1.f / 127.f);

    // 256 int8 weights in 16 named 128-bit registers (64 VGPRs)
    const u32x4* wr = (const u32x4*)(w8 + (size_t)r * D + hf * 256);
    u32x4 w0  = wr[0],  w1  = wr[1],  w2  = wr[2],  w3  = wr[3];
    u32x4 w4  = wr[4],  w5  = wr[5],  w6  = wr[6],  w7  = wr[7];
    u32x4 w8v = wr[8],  w9  = wr[9],  w10 = wr[10], w11 = wr[11];
    u32x4 w12 = wr[12], w13 = wr[13], w14 = wr[14], w15 = wr[15];

    if (hf == 0) {
        float h0v = fminf(fmaxf(h0[r], -0.999f), 0.999f);
        hq[0][r] = (int8_t)__float2int_rn(h0v * 127.f);
    }
    __syncthreads();

    int p = 0;
    for (int step = 0; step < NSTEP; step++) {
        // opaque per-iteration redefinition: no remat, no sinking, must stay in regs
        asm volatile("" : "+v"(w0), "+v"(w1), "+v"(w2),  "+v"(w3),
                          "+v"(w4), "+v"(w5), "+v"(w6),  "+v"(w7),
                          "+v"(w8v),"+v"(w9), "+v"(w10), "+v"(w11),
                          "+v"(w12),"+v"(w13),"+v"(w14), "+v"(w15));
        float prev = pre[(size_t)step * D + r];    // lane-pair broadcast, L2-hot
        const u32x4* hv = (const u32x4*)(&hq[p][hf * 256]);
        int a0 = 0, a1 = 0, a2 = 0, a3 = 0;
        #define DOT_STEP(i, wv) { u32x4 hx = hv[i];            \
            a0 = sdot4((int)(wv).x, (int)hx.x, a0);            \
            a1 = sdot4((int)(wv).y, (int)hx.y, a1);            \
            a2 = sdot4((int)(wv).z, (int)hx.z, a2);            \
            a3 = sdot4((int)(wv).w, (int)hx.w, a3); }
        DOT_STEP(0,  w0)  DOT_STEP(1,  w1)  DOT_STEP(2,  w2)  DOT_STEP(3,  w3)
        DOT_STEP(4,  w4)  DOT_STEP(5,  w5)  DOT_STEP(6,  w6)  DOT_STEP(7,  w7)
        DOT_STEP(8,  w8v) DOT_STEP(9,  w9)  DOT_STEP(10, w10) DOT_STEP(11, w11)
        DOT_STEP(12, w12) DOT_STEP(13, w13) DOT_STEP(14, w14) DOT_STEP(15, w15)
        #undef DOT_STEP
        int acc = (a0 + a1) + (a2 + a3);
        acc += __shfl_xor(acc, 1);                 // combine the two half-rows
        if (hf == 0) {
            float h2 = tanhf(prev + (float)acc * sw);
            hs[(size_t)step * D + r] = h2;
            hq[p ^ 1][r] = (int8_t)__float2int_rn(h2 * 127.f);
        }
        p ^= 1;
        __syncthreads();
    }
}

// ---- K3: per decoder step: attention + m = tanh([c,h2] @ Wm^T + bm) -> int8 ----
__global__ __launch_bounds__(512) void k_att(
        const float* __restrict__ fencs, const float* __restrict__ h2s,
        const float* __restrict__ Wm, const float* __restrict__ bm,
        int8_t* __restrict__ mq) {
    __shared__ float h2l[D], cl[D], sc[NSTEP], red[64];
    __shared__ float ftile[32 * D];     // 64 KB staged fencs tile
    int s = blockIdx.x, t = threadIdx.x;
    h2l[t] = h2s[(size_t)s * D + t];
    __syncthreads();

    {   // scores[j] = fencs[j] . h2 ; thread (j = t>>2, q = t&3)
        int j = t >> 2, q = t & 3;
        const float4* fr = (const float4*)(fencs + (size_t)j * D + q * 128);
        const float4* hr = (const float4*)(h2l + q * 128);
        float acc = 0.f;
        #pragma unroll 8
        for (int k4 = 0; k4 < 32; k4++) {
            float4 f = fr[k4], hh = hr[k4];
            acc += f.x*hh.x + f.y*hh.y + f.z*hh.z + f.w*hh.w;
        }
        acc += __shfl_xor(acc, 1);
        acc += __shfl_xor(acc, 2);
        if (q == 0) sc[j] = acc;
    }
    __syncthreads();
    if (t < 64) {
        float m = fmaxf(sc[t], sc[t + 64]);
        for (int off = 32; off; off >>= 1) m = fmaxf(m, __shfl_xor(m, off));
        if (t == 0) red[0] = m;
    }
    __syncthreads();
    float mx = red[0];
    __syncthreads();
    if (t < NSTEP) sc[t] = expf(sc[t] - mx);
    __syncthreads();
    if (t < 64) {
        float v = sc[t] + sc[t + 64];
        for (int off = 32; off; off >>= 1) v += __shfl_xor(v, off);
        if (t == 0) red[0] = v;
    }
    __syncthreads();
    float inv = 1.0f / red[0];

    // c[k] = sum_j alpha[j]*fencs[j][k], via 4 staged 32-row tiles
    float cacc = 0.f;
    for (int jt = 0; jt < 4; jt++) {
        #pragma unroll
        for (int k = 0; k < 32; k++)
            ftile[t + k * D] = fencs[(size_t)jt * 32 * D + t + k * D];
        __syncthreads();
        #pragma unroll 8
        for (int j = 0; j < 32; j++)
            cacc += sc[jt * 32 + j] * ftile[j * D + t];   // bank = t%32, clean
        __syncthreads();
    }
    cl[t] = cacc * inv;
    __syncthreads();

    {   // m[o] = tanh(Wm[o,:512].c + Wm[o,512:].h2 + bm), o = t
        float acc = bm[t];
        const float4* wr = (const float4*)(Wm + (size_t)t * 2 * D);
        const float4* cr = (const float4*)cl;
        const float4* hr = (const float4*)h2l;
        #pragma unroll 4
        for (int k4 = 0; k4 < D / 4; k4++) {
            float4 w = wr[k4], c = cr[k4];
            acc += w.x*c.x + w.y*c.y + w.z*c.z + w.w*c.w;
        }
        #pragma unroll 4
        for (int k4 = 0; k4 < D / 4; k4++) {
            float4 w = wr[D/4 + k4], hh = hr[k4];
            acc += w.x*hh.x + w.y*hh.y + w.z*hh.z + w.w*hh.w;
        }
        mq[(size_t)s * D + t] = (int8_t)__float2int_rn(tanhf(acc) * 127.f);
    }
}

// ---- K4: int8 logits GEMM (128 steps x 128 vocab, K=512) + fused row max/sumexp ----
__global__ __launch_bounds__(512) void k_logits(
        const int8_t* __restrict__ mq, const int8_t* __restrict__ woq,
        const float* __restrict__ wosc, const float* __restrict__ bo,
        const int* __restrict__ enums,
        float* __restrict__ pmax, float* __restrict__ psum, float* __restrict__ pick) {
    __shared__ uint32_t a_s[128 * LDA_W];   // 18.4 KB
    __shared__ uint32_t b_s[32 * LDB_W];    // 16.5 KB
    int b = blockIdx.x, t = threadIdx.x;
    int v0 = b * VTILE;
    int ti = t >> 5, tj = t & 31;           // out: rows ti*8+i, cols tj+32*jj
    int lrow = t >> 3, lq = t & 7;          // staging: 64 rows/rep, 8 16B-quads/row
    int acc[8][4] = {};

    for (int kc = 0; kc < 4; kc++) {        // K chunks of 128 int8 (32 words)
        #pragma unroll
        for (int rep = 0; rep < 2; rep++) {
            int row = lrow + rep * 64;
            uint4 av = *(const uint4*)(mq + (size_t)row * D + kc * 128 + lq * 16);
            *(uint4*)&a_s[row * LDA_W + lq * 4] = av;
            int v = v0 + row;
            uint4 bv = (v < EVOC)
                ? *(const uint4*)(woq + (size_t)v * D + kc * 128 + lq * 16)
                : make_uint4(0u, 0u, 0u, 0u);
            b_s[(lq*4+0) * LDB_W + row] = bv.x;
            b_s[(lq*4+1) * LDB_W + row] = bv.y;
            b_s[(lq*4+2) * LDB_W + row] = bv.z;
            b_s[(lq*4+3) * LDB_W + row] = bv.w;
        }
        __syncthreads();
        #pragma unroll
        for (int q = 0; q < 8; q++) {
            uint4 aw[8];
            #pragma unroll
            for (int i = 0; i < 8; i++)
                aw[i] = *(const uint4*)&a_s[(ti*8 + i) * LDA_W + q*4];
            #pragma unroll
            for (int k4 = 0; k4 < 4; k4++) {
                uint32_t bw[4];
                #pragma unroll
                for (int jj = 0; jj < 4; jj++)
                    bw[jj] = b_s[(q*4 + k4) * LDB_W + tj + 32*jj];
                #pragma unroll
                for (int i = 0; i < 8; i++) {
                    uint32_t a = (k4 == 0) ? aw[i].x : (k4 == 1) ? aw[i].y
                               : (k4 == 2) ? aw[i].z : aw[i].w;
                    #pragma unroll
                    for (int jj = 0; jj < 4; jj++)
                        acc[i][jj] = sdot4((int)a, (int)bw[jj], acc[i][jj]);
                }
            }
        }
        __syncthreads();
    }

    float sw4[4], bo4[4];
    int vld[4];
    #pragma unroll
    for (int jj = 0; jj < 4; jj++) {
        int v = v0 + tj + 32*jj;
        vld[jj] = (v < EVOC);
        sw4[jj] = vld[jj] ? wosc[v] * (1.f/127.f) : 0.f;
        bo4[jj] = vld[jj] ? bo[v] : 0.f;
    }
    #pragma unroll
    for (int i = 0; i < 8; i++) {
        int s = ti * 8 + i;
        float l[4];
        float mx = -1e30f;
        #pragma unroll
        for (int jj = 0; jj < 4; jj++) {
            l[jj] = vld[jj] ? (float)acc[i][jj] * sw4[jj] + bo4[jj] : -1e30f;
            mx = fmaxf(mx, l[jj]);
        }
        #pragma unroll
        for (int off = 1; off < 32; off <<= 1) mx = fmaxf(mx, __shfl_xor(mx, off));
        float sm = 0.f;
        #pragma unroll
        for (int jj = 0; jj < 4; jj++)
            if (vld[jj]) sm += expf(l[jj] - mx);
        #pragma unroll
        for (int off = 1; off < 32; off <<= 1) sm += __shfl_xor(sm, off);
        if (tj == 0) { pmax[b * NSTEP + s] = mx; psum[b * NSTEP + s] = sm; }
        int tgt = enums[s + 1];
        if (tgt >= v0 && tgt < v0 + VTILE) {
            int c = tgt - v0;
            if ((c & 31) == tj) pick[s] = l[c >> 5];
        }
    }
}

// ---- K5: combine partial logsumexps, pick target logprobs, sum ----
__global__ void k_final(const float* __restrict__ pmax, const float* __restrict__ psum,
                        const float* __restrict__ pick, float* __restrict__ out) {
    __shared__ float red[NSTEP];
    int t = threadIdx.x;     // 128 threads, one per decoder step
    float M = -1e30f;
    for (int b = 0; b < NBV; b++) M = fmaxf(M, pmax[b * NSTEP + t]);
    float S = 0.f;
    for (int b = 0; b < NBV; b++) S += psum[b * NSTEP + t] * expf(pmax[b * NSTEP + t] - M);
    red[t] = pick[t] - (M + logf(S));
    __syncthreads();
    for (int off = 64; off > 0; off >>= 1) {
        if (t < off) red[t] += red[t + off];
        __syncthreads();
    }
    if (t == 0) out[0] = red[0];
}

extern "C" void kernel_launch(void* const* d_in, const int* in_sizes, int n_in,
                              void* d_out, int out_size, void* d_ws, size_t ws_size,
                              hipStream_t stream) {
    const int*   fnums = (const int*)  d_in[0];
    const int*   enums = (const int*)  d_in[1];
    const float* emb_f = (const float*)d_in[2];
    const float* Wih_e = (const float*)d_in[3];
    const float* Whh_e = (const float*)d_in[4];
    const float* b_e   = (const float*)d_in[5];
    const float* h0_e  = (const float*)d_in[6];
    const float* emb_d = (const float*)d_in[7];
    const float* Wih_d = (const float*)d_in[8];
    const float* Whh_d = (const float*)d_in[9];
    const float* b_d   = (const float*)d_in[10];
    const float* h0_d  = (const float*)d_in[11];
    const float* Wm    = (const float*)d_in[12];
    const float* bm    = (const float*)d_in[13];
    const float* Wo    = (const float*)d_in[14];
    const float* bo    = (const float*)d_in[15];

    float* ws = (float*)d_ws;
    float* pre_e = ws;                       // 65536
    float* pre_d = ws + 65536;               // 65536
    float* fencs = ws + 131072;              // 65536
    float* h2s   = ws + 196608;              // 65536
    float* pmax  = ws + 262144;              // 50048
    float* psum  = ws + 312192;              // 50048
    float* pick  = ws + 362240;              // 128
    float* qsc   = ws + 362368;              // 1024
    int8_t* q8   = (int8_t*)(ws + 363392);   // 512 KB int8 scan weights
    float* wosc  = ws + 494464;              // 50048
    int8_t* mq   = (int8_t*)(ws + 544512);   // 64 KB
    int8_t* woq  = (int8_t*)(ws + 560896);   // 25.6 MB

    k_quant<<<dim3(1024), dim3(64), 0, stream>>>(Whh_e, Whh_d, q8, qsc);
    k_quant_wo<<<dim3((EVOC + 3) / 4), dim3(256), 0, stream>>>(Wo, woq, wosc);
    k_pre<<<dim3(256), dim3(256), 0, stream>>>(fnums, enums, emb_f, emb_d,
                                               Wih_e, Wih_d, b_e, b_d, pre_e, pre_d);
    k_scan<<<dim3(2), dim3(1024), 0, stream>>>(q8, qsc, pre_e, pre_d, h0_e, h0_d, fencs, h2s);
    k_att<<<dim3(NSTEP), dim3(512), 0, stream>>>(fencs, h2s, Wm, bm, mq);
    k_logits<<<dim3(NBV), dim3(512), 0, stream>>>(mq, woq, wosc, bo, enums, pmax, psum, pick);
    k_final<<<dim3(1), dim3(NSTEP), 0, stream>>>(pmax, psum, pick, (float*)d_out);
}

// Round 12
// 414.897 us; speedup vs baseline: 1.3347x; 1.0806x over previous
//
#include <hip/hip_runtime.h>
#include <stdint.h>

#define D      512
#define NSTEP  128          // SRC steps == decoder steps (TGT-1)
#define EVOC   50000
#define VTILE  128
#define NBV    ((EVOC + VTILE - 1) / VTILE)   // 391
#define LDA_W  36           // A LDS row stride in u32 words (144 B, 16B-aligned)
#define LDB_W  132          // B LDS kw-row stride in u32 words (16B-aligned for b128 col reads)
#define WO_BLK ((EVOC + 3) / 4)               // 12500

typedef unsigned int u32x4 __attribute__((ext_vector_type(4)));

// ---- int8 dot4 (v_dot4_i32_i8) ----
__device__ inline int sdot4(int a, int b, int c) {
#if __has_builtin(__builtin_amdgcn_sdot4)
    return __builtin_amdgcn_sdot4(a, b, c, false);
#else
    int r = c;
    r += (int)(int8_t)(a)       * (int)(int8_t)(b);
    r += (int)(int8_t)(a >> 8)  * (int)(int8_t)(b >> 8);
    r += (int)(int8_t)(a >> 16) * (int)(int8_t)(b >> 16);
    r += (int)(int8_t)(a >> 24) * (int)(int8_t)(b >> 24);
    return r;
#endif
}

__device__ inline uint32_t pack4(float a, float b, float c, float d, float inv) {
    return  ((uint32_t)(uint8_t)(int8_t)__float2int_rn(a * inv)) |
            ((uint32_t)(uint8_t)(int8_t)__float2int_rn(b * inv) << 8) |
            ((uint32_t)(uint8_t)(int8_t)__float2int_rn(c * inv) << 16) |
            ((uint32_t)(uint8_t)(int8_t)__float2int_rn(d * inv) << 24);
}

__device__ inline float amax4(float4 v) {
    return fmaxf(fmaxf(fabsf(v.x), fabsf(v.y)), fmaxf(fabsf(v.z), fabsf(v.w)));
}

// ---- K_PREP: fused (whh quant | wm quant | wo quant->woq2 | pre matvec) ----
// All four jobs are independent; fusing them makes them run CONCURRENTLY
// instead of serializing on the single stream (saves ~20-30us + 3 gaps).
__global__ __launch_bounds__(256) void k_prep(
        const float* __restrict__ We,   const float* __restrict__ Wd,
        const float* __restrict__ Wm,   const float* __restrict__ Wo,
        const int* __restrict__ fnums,  const int* __restrict__ enums,
        const float* __restrict__ emb_f,const float* __restrict__ emb_d,
        const float* __restrict__ Wih_e,const float* __restrict__ Wih_d,
        const float* __restrict__ b_e,  const float* __restrict__ b_d,
        int8_t* __restrict__ q8,  float* __restrict__ qsc,
        int8_t* __restrict__ wmq, float* __restrict__ wmsc,
        uint32_t* __restrict__ woq2, float* __restrict__ wosc,
        float* __restrict__ pre_e, float* __restrict__ pre_d) {
    __shared__ float xl[D];
    int bid = blockIdx.x, t = threadIdx.x;
    int lane = t & 63;

    if (bid < 256) {                       // --- whh int8 quant, 4 rows/block ---
        int rg = bid * 4 + (t >> 6);       // 0..1023
        int which = rg >> 9, row = rg & 511;
        const float* W = which ? Wd : We;
        const float4* src = (const float4*)(W + (size_t)row * D);
        float4 v0 = src[lane], v1 = src[lane + 64];
        float m = fmaxf(amax4(v0), amax4(v1));
        for (int off = 32; off; off >>= 1) m = fmaxf(m, __shfl_xor(m, off));
        float inv = (m > 0.f) ? 127.f / m : 0.f;
        uint32_t* dst = (uint32_t*)(q8 + (size_t)which * D * D + (size_t)row * D);
        dst[lane]      = pack4(v0.x, v0.y, v0.z, v0.w, inv);   // word w = cols 4w..4w+3
        dst[lane + 64] = pack4(v1.x, v1.y, v1.z, v1.w, inv);
        if (lane == 0) qsc[which * D + row] = m / 127.f;
    } else if (bid < 384) {                // --- Wm int8 quant (512 rows x 1024) ---
        int row = (bid - 256) * 4 + (t >> 6);   // 0..511
        const float4* src = (const float4*)(Wm + (size_t)row * 2 * D);
        float4 a = src[lane], b = src[lane + 64], c = src[lane + 128], d2 = src[lane + 192];
        float m = fmaxf(fmaxf(amax4(a), amax4(b)), fmaxf(amax4(c), amax4(d2)));
        for (int off = 32; off; off >>= 1) m = fmaxf(m, __shfl_xor(m, off));
        float inv = (m > 0.f) ? 127.f / m : 0.f;
        uint32_t* dst = (uint32_t*)(wmq + (size_t)row * 2 * D);
        dst[lane]       = pack4(a.x, a.y, a.z, a.w, inv);
        dst[lane + 64]  = pack4(b.x, b.y, b.z, b.w, inv);
        dst[lane + 128] = pack4(c.x, c.y, c.z, c.w, inv);
        dst[lane + 192] = pack4(d2.x, d2.y, d2.z, d2.w, inv);
        if (lane == 0) wmsc[row] = m / 127.f;
    } else if (bid < 384 + WO_BLK) {       // --- Wo int8 quant -> kc-blocked woq2 ---
        int row = (bid - 384) * 4 + (t >> 6);
        if (row < EVOC) {
            const float4* src = (const float4*)(Wo + (size_t)row * D);
            float4 v0 = src[lane], v1 = src[lane + 64];
            float m = fmaxf(amax4(v0), amax4(v1));
            for (int off = 32; off; off >>= 1) m = fmaxf(m, __shfl_xor(m, off));
            float inv = (m > 0.f) ? 127.f / m : 0.f;
            // woq2 word index: ((v>>7)*4 + (w>>5))*4096 + (v&127)*32 + (w&31)
            // -> k_logits' staging loads become one linear coalesced stream.
            uint32_t w1 = pack4(v0.x, v0.y, v0.z, v0.w, inv);
            uint32_t w2 = pack4(v1.x, v1.y, v1.z, v1.w, inv);
            int wA = lane, wB = lane + 64;
            woq2[((size_t)(row >> 7) * 4 + (wA >> 5)) * 4096 + (size_t)(row & 127) * 32 + (wA & 31)] = w1;
            woq2[((size_t)(row >> 7) * 4 + (wB >> 5)) * 4096 + (size_t)(row & 127) * 32 + (wB & 31)] = w2;
            if (lane == 0) wosc[row] = m / 127.f;
        }
    } else {                               // --- pre matvec (256 blocks) ---
        int bb = bid - (384 + WO_BLK);
        int kind = bb >> 7, s = bb & 127;
        const float* emb = kind ? emb_d : emb_f;
        int idx          = kind ? enums[s] : fnums[s];
        const float* W   = kind ? Wih_d : Wih_e;
        const float* b   = kind ? b_d : b_e;
        float* pre       = kind ? pre_d : pre_e;
        xl[t]       = emb[(size_t)idx * D + t];
        xl[t + 256] = emb[(size_t)idx * D + t + 256];
        __syncthreads();
        for (int rep = 0; rep < 2; rep++) {
            int o = t + rep * 256;
            float acc = b[o];
            const float4* Wr = (const float4*)(W + (size_t)o * D);
            #pragma unroll 8
            for (int k4 = 0; k4 < D / 4; k4++) {
                float4 w = Wr[k4];
                acc += w.x * xl[4*k4] + w.y * xl[4*k4+1] + w.z * xl[4*k4+2] + w.w * xl[4*k4+3];
            }
            pre[(size_t)s * D + o] = acc;
        }
    }
}

// ---- K2: the two sequential scans (FROZEN at 184us: per-CU L2-BW roofline of
// the 256KB/step weight stream; 6 register-residency attempts all failed). ----
__global__ __launch_bounds__(1024)
__attribute__((amdgpu_waves_per_eu(4, 4)))
void k_scan(
        const int8_t* __restrict__ q8, const float* __restrict__ qsc,
        const float* __restrict__ pre_e, const float* __restrict__ pre_d,
        const float* __restrict__ h0_e, const float* __restrict__ h0_d,
        float* __restrict__ fencs, float* __restrict__ h2s) {
    __shared__ __align__(16) int8_t hq[2][D];
    int t = threadIdx.x;
    int r = t >> 1, hf = t & 1;
    int which = blockIdx.x;
    const int8_t* w8 = q8 + (size_t)which * D * D;
    const float*  pre = which ? pre_d : pre_e;
    const float*  h0  = which ? h0_d : h0_e;
    float*        hs  = which ? h2s : fencs;
    float sw = qsc[which * D + r] * (1.f / 127.f);

    const u32x4* wr = (const u32x4*)(w8 + (size_t)r * D + hf * 256);
    u32x4 w0  = wr[0],  w1  = wr[1],  w2  = wr[2],  w3  = wr[3];
    u32x4 w4  = wr[4],  w5  = wr[5],  w6  = wr[6],  w7  = wr[7];
    u32x4 w8v = wr[8],  w9  = wr[9],  w10 = wr[10], w11 = wr[11];
    u32x4 w12 = wr[12], w13 = wr[13], w14 = wr[14], w15 = wr[15];

    if (hf == 0) {
        float h0v = fminf(fmaxf(h0[r], -0.999f), 0.999f);
        hq[0][r] = (int8_t)__float2int_rn(h0v * 127.f);
    }
    __syncthreads();

    int p = 0;
    for (int step = 0; step < NSTEP; step++) {
        asm volatile("" : "+v"(w0), "+v"(w1), "+v"(w2),  "+v"(w3),
                          "+v"(w4), "+v"(w5), "+v"(w6),  "+v"(w7),
                          "+v"(w8v),"+v"(w9), "+v"(w10), "+v"(w11),
                          "+v"(w12),"+v"(w13),"+v"(w14), "+v"(w15));
        float prev = pre[(size_t)step * D + r];
        const u32x4* hv = (const u32x4*)(&hq[p][hf * 256]);
        int a0 = 0, a1 = 0, a2 = 0, a3 = 0;
        #define DOT_STEP(i, wv) { u32x4 hx = hv[i];            \
            a0 = sdot4((int)(wv).x, (int)hx.x, a0);            \
            a1 = sdot4((int)(wv).y, (int)hx.y, a1);            \
            a2 = sdot4((int)(wv).z, (int)hx.z, a2);            \
            a3 = sdot4((int)(wv).w, (int)hx.w, a3); }
        DOT_STEP(0,  w0)  DOT_STEP(1,  w1)  DOT_STEP(2,  w2)  DOT_STEP(3,  w3)
        DOT_STEP(4,  w4)  DOT_STEP(5,  w5)  DOT_STEP(6,  w6)  DOT_STEP(7,  w7)
        DOT_STEP(8,  w8v) DOT_STEP(9,  w9)  DOT_STEP(10, w10) DOT_STEP(11, w11)
        DOT_STEP(12, w12) DOT_STEP(13, w13) DOT_STEP(14, w14) DOT_STEP(15, w15)
        #undef DOT_STEP
        int acc = (a0 + a1) + (a2 + a3);
        acc += __shfl_xor(acc, 1);
        if (hf == 0) {
            float h2 = tanhf(prev + (float)acc * sw);
            hs[(size_t)step * D + r] = h2;
            hq[p ^ 1][r] = (int8_t)__float2int_rn(h2 * 127.f);
        }
        p ^= 1;
        __syncthreads();
    }
}

// ---- K3a: attention scores + softmax + context -> chq = int8 [c | h2] ----
// (m-matvec removed: it re-read the 2MB Wm 128x, L2-latency-bound -> k_att2 GEMM)
__global__ __launch_bounds__(512) void k_att1(
        const float* __restrict__ fencs, const float* __restrict__ h2s,
        int8_t* __restrict__ chq) {
    __shared__ float h2l[D], sc[NSTEP], red[64];
    __shared__ float ftile[32 * D];
    int s = blockIdx.x, t = threadIdx.x;
    h2l[t] = h2s[(size_t)s * D + t];
    __syncthreads();

    {   // scores[j] = fencs[j] . h2 ; thread (j = t>>2, q = t&3)
        int j = t >> 2, q = t & 3;
        const float4* fr = (const float4*)(fencs + (size_t)j * D + q * 128);
        const float4* hr = (const float4*)(h2l + q * 128);
        float acc = 0.f;
        #pragma unroll 8
        for (int k4 = 0; k4 < 32; k4++) {
            float4 f = fr[k4], hh = hr[k4];
            acc += f.x*hh.x + f.y*hh.y + f.z*hh.z + f.w*hh.w;
        }
        acc += __shfl_xor(acc, 1);
        acc += __shfl_xor(acc, 2);
        if (q == 0) sc[j] = acc;
    }
    __syncthreads();
    if (t < 64) {
        float m = fmaxf(sc[t], sc[t + 64]);
        for (int off = 32; off; off >>= 1) m = fmaxf(m, __shfl_xor(m, off));
        if (t == 0) red[0] = m;
    }
    __syncthreads();
    float mx = red[0];
    __syncthreads();
    if (t < NSTEP) sc[t] = expf(sc[t] - mx);
    __syncthreads();
    if (t < 64) {
        float v = sc[t] + sc[t + 64];
        for (int off = 32; off; off >>= 1) v += __shfl_xor(v, off);
        if (t == 0) red[0] = v;
    }
    __syncthreads();
    float inv = 1.0f / red[0];

    float cacc = 0.f;
    for (int jt = 0; jt < 4; jt++) {
        #pragma unroll
        for (int k = 0; k < 32; k++)
            ftile[t + k * D] = fencs[(size_t)jt * 32 * D + t + k * D];
        __syncthreads();
        #pragma unroll 8
        for (int j = 0; j < 32; j++)
            cacc += sc[jt * 32 + j] * ftile[j * D + t];
        __syncthreads();
    }
    float cv = cacc * inv;                        // |c| < 1 (convex combo of tanh)
    chq[(size_t)s * 2 * D + t]     = (int8_t)__float2int_rn(cv * 127.f);
    chq[(size_t)s * 2 * D + D + t] = (int8_t)__float2int_rn(h2l[t] * 127.f);
}

// ---- K3b: m = tanh([c,h2] @ Wm^T + bm) as ONE int8 GEMM (Wm read once) ----
// 128 x 512, K=1024. Same tile structure as k_logits; grid 4 x 128 cols.
__global__ __launch_bounds__(512) void k_att2(
        const int8_t* __restrict__ chq, const int8_t* __restrict__ wmq,
        const float* __restrict__ wmsc, const float* __restrict__ bm,
        int8_t* __restrict__ mq) {
    __shared__ __align__(16) uint32_t a_s[128 * LDA_W];
    __shared__ __align__(16) uint32_t b_s[32 * LDB_W];
    int t = threadIdx.x;
    int v0 = blockIdx.x * VTILE;            // col tile base (N=512)
    int ti = t >> 5, tj = t & 31;           // rows ti*8+i, cols tj*4+jj (contiguous)
    int lrow = t >> 3, lq = t & 7;
    int acc[8][4] = {};

    for (int kc = 0; kc < 8; kc++) {        // K = 1024 -> 8 chunks of 128
        #pragma unroll
        for (int rep = 0; rep < 2; rep++) {
            int row = lrow + rep * 64;
            uint4 av = *(const uint4*)(chq + (size_t)row * 2 * D + kc * 128 + lq * 16);
            *(uint4*)&a_s[row * LDA_W + lq * 4] = av;
            int v = v0 + row;
            uint4 bv = *(const uint4*)(wmq + (size_t)v * 2 * D + kc * 128 + lq * 16);
            b_s[(lq*4+0) * LDB_W + row] = bv.x;
            b_s[(lq*4+1) * LDB_W + row] = bv.y;
            b_s[(lq*4+2) * LDB_W + row] = bv.z;
            b_s[(lq*4+3) * LDB_W + row] = bv.w;
        }
        __syncthreads();
        #pragma unroll
        for (int q = 0; q < 8; q++) {
            uint4 aw[8];
            #pragma unroll
            for (int i = 0; i < 8; i++)
                aw[i] = *(const uint4*)&a_s[(ti*8 + i) * LDA_W + q*4];
            #pragma unroll
            for (int k4 = 0; k4 < 4; k4++) {
                uint4 bw = *(const uint4*)&b_s[(q*4 + k4) * LDB_W + tj * 4];
                #pragma unroll
                for (int i = 0; i < 8; i++) {
                    uint32_t a = (k4 == 0) ? aw[i].x : (k4 == 1) ? aw[i].y
                               : (k4 == 2) ? aw[i].z : aw[i].w;
                    acc[i][0] = sdot4((int)a, (int)bw.x, acc[i][0]);
                    acc[i][1] = sdot4((int)a, (int)bw.y, acc[i][1]);
                    acc[i][2] = sdot4((int)a, (int)bw.z, acc[i][2]);
                    acc[i][3] = sdot4((int)a, (int)bw.w, acc[i][3]);
                }
            }
        }
        __syncthreads();
    }

    float sw4[4], bm4[4];
    #pragma unroll
    for (int jj = 0; jj < 4; jj++) {
        int col = v0 + tj * 4 + jj;
        sw4[jj] = wmsc[col] * (1.f / (127.f * 127.f));
        bm4[jj] = bm[col];
    }
    #pragma unroll
    for (int i = 0; i < 8; i++) {
        int s = ti * 8 + i;
        float m0 = tanhf((float)acc[i][0] * sw4[0] + bm4[0]);
        float m1 = tanhf((float)acc[i][1] * sw4[1] + bm4[1]);
        float m2 = tanhf((float)acc[i][2] * sw4[2] + bm4[2]);
        float m3 = tanhf((float)acc[i][3] * sw4[3] + bm4[3]);
        ((uint32_t*)mq)[(size_t)s * (D / 4) + (v0 >> 2) + tj] = pack4(m0, m1, m2, m3, 127.f);
    }
}

// ---- K4: int8 logits GEMM + fused row max/sumexp. b128 column reads (4
// consecutive cols/lane) halve LDS instrs; woq2 staging is fully coalesced. ----
__global__ __launch_bounds__(512) void k_logits(
        const int8_t* __restrict__ mq, const uint32_t* __restrict__ woq2,
        const float* __restrict__ wosc, const float* __restrict__ bo,
        const int* __restrict__ enums,
        float* __restrict__ pmax, float* __restrict__ psum, float* __restrict__ pick) {
    __shared__ __align__(16) uint32_t a_s[128 * LDA_W];
    __shared__ __align__(16) uint32_t b_s[32 * LDB_W];
    int b = blockIdx.x, t = threadIdx.x;
    int v0 = b * VTILE;
    int ti = t >> 5, tj = t & 31;           // rows ti*8+i, cols tj*4+jj
    int lrow = t >> 3, lq = t & 7;
    int acc[8][4] = {};

    for (int kc = 0; kc < 4; kc++) {
        const uint4* bsrc = (const uint4*)(woq2 + ((size_t)b * 4 + kc) * 4096);
        #pragma unroll
        for (int rep = 0; rep < 2; rep++) {
            int row = lrow + rep * 64;
            uint4 av = *(const uint4*)(mq + (size_t)row * D + kc * 128 + lq * 16);
            *(uint4*)&a_s[row * LDA_W + lq * 4] = av;
            uint4 bv = bsrc[t + rep * 512];        // linear coalesced (pad rows masked below)
            b_s[(lq*4+0) * LDB_W + row] = bv.x;
            b_s[(lq*4+1) * LDB_W + row] = bv.y;
            b_s[(lq*4+2) * LDB_W + row] = bv.z;
            b_s[(lq*4+3) * LDB_W + row] = bv.w;
        }
        __syncthreads();
        #pragma unroll
        for (int q = 0; q < 8; q++) {
            uint4 aw[8];
            #pragma unroll
            for (int i = 0; i < 8; i++)
                aw[i] = *(const uint4*)&a_s[(ti*8 + i) * LDA_W + q*4];
            #pragma unroll
            for (int k4 = 0; k4 < 4; k4++) {
                uint4 bw = *(const uint4*)&b_s[(q*4 + k4) * LDB_W + tj * 4];
                #pragma unroll
                for (int i = 0; i < 8; i++) {
                    uint32_t a = (k4 == 0) ? aw[i].x : (k4 == 1) ? aw[i].y
                               : (k4 == 2) ? aw[i].z : aw[i].w;
                    acc[i][0] = sdot4((int)a, (int)bw.x, acc[i][0]);
                    acc[i][1] = sdot4((int)a, (int)bw.y, acc[i][1]);
                    acc[i][2] = sdot4((int)a, (int)bw.z, acc[i][2]);
                    acc[i][3] = sdot4((int)a, (int)bw.w, acc[i][3]);
                }
            }
        }
        __syncthreads();
    }

    float sw4[4], bo4[4];
    int vld[4];
    #pragma unroll
    for (int jj = 0; jj < 4; jj++) {
        int v = v0 + tj * 4 + jj;
        vld[jj] = (v < EVOC);
        sw4[jj] = vld[jj] ? wosc[v] * (1.f / 127.f) : 0.f;
        bo4[jj] = vld[jj] ? bo[v] : 0.f;
    }
    #pragma unroll
    for (int i = 0; i < 8; i++) {
        int s = ti * 8 + i;
        float l[4];
        float mx = -1e30f;
        #pragma unroll
        for (int jj = 0; jj < 4; jj++) {
            l[jj] = vld[jj] ? (float)acc[i][jj] * sw4[jj] + bo4[jj] : -1e30f;
            mx = fmaxf(mx, l[jj]);
        }
        #pragma unroll
        for (int off = 1; off < 32; off <<= 1) mx = fmaxf(mx, __shfl_xor(mx, off));
        float sm = 0.f;
        #pragma unroll
        for (int jj = 0; jj < 4; jj++)
            if (vld[jj]) sm += expf(l[jj] - mx);
        #pragma unroll
        for (int off = 1; off < 32; off <<= 1) sm += __shfl_xor(sm, off);
        if (tj == 0) { pmax[b * NSTEP + s] = mx; psum[b * NSTEP + s] = sm; }
        int tgt = enums[s + 1];
        if (tgt >= v0 && tgt < v0 + VTILE) {
            int c = tgt - v0;
            if ((c >> 2) == tj) pick[s] = l[c & 3];
        }
    }
}

// ---- K5a: per-step logsumexp combine, 128 blocks in parallel ----
__global__ __launch_bounds__(256) void k_final_par(
        const float* __restrict__ pmax, const float* __restrict__ psum,
        const float* __restrict__ pick, float* __restrict__ lp) {
    __shared__ float red[8];
    int s = blockIdx.x, t = threadIdx.x;
    float M = -1e30f;
    for (int b = t; b < NBV; b += 256) M = fmaxf(M, pmax[b * NSTEP + s]);
    for (int off = 32; off; off >>= 1) M = fmaxf(M, __shfl_xor(M, off));
    if ((t & 63) == 0) red[t >> 6] = M;
    __syncthreads();
    M = fmaxf(fmaxf(red[0], red[1]), fmaxf(red[2], red[3]));
    float S = 0.f;
    for (int b = t; b < NBV; b += 256) S += psum[b * NSTEP + s] * expf(pmax[b * NSTEP + s] - M);
    for (int off = 32; off; off >>= 1) S += __shfl_xor(S, off);
    if ((t & 63) == 0) red[4 + (t >> 6)] = S;
    __syncthreads();
    if (t == 0) {
        S = red[4] + red[5] + red[6] + red[7];
        lp[s] = pick[s] - (M + logf(S));
    }
}

// ---- K5b: sum 128 logprobs ----
__global__ void k_final_sum(const float* __restrict__ lp, float* __restrict__ out) {
    __shared__ float red[NSTEP];
    int t = threadIdx.x;
    red[t] = lp[t];
    __syncthreads();
    for (int off = 64; off > 0; off >>= 1) {
        if (t < off) red[t] += red[t + off];
        __syncthreads();
    }
    if (t == 0) out[0] = red[0];
}

extern "C" void kernel_launch(void* const* d_in, const int* in_sizes, int n_in,
                              void* d_out, int out_size, void* d_ws, size_t ws_size,
                              hipStream_t stream) {
    const int*   fnums = (const int*)  d_in[0];
    const int*   enums = (const int*)  d_in[1];
    const float* emb_f = (const float*)d_in[2];
    const float* Wih_e = (const float*)d_in[3];
    const float* Whh_e = (const float*)d_in[4];
    const float* b_e   = (const float*)d_in[5];
    const float* h0_e  = (const float*)d_in[6];
    const float* emb_d = (const float*)d_in[7];
    const float* Wih_d = (const float*)d_in[8];
    const float* Whh_d = (const float*)d_in[9];
    const float* b_d   = (const float*)d_in[10];
    const float* h0_d  = (const float*)d_in[11];
    const float* Wm    = (const float*)d_in[12];
    const float* bm    = (const float*)d_in[13];
    const float* Wo    = (const float*)d_in[14];
    const float* bo    = (const float*)d_in[15];

    float* ws = (float*)d_ws;
    float* pre_e = ws;                        // 65536
    float* pre_d = ws + 65536;                // 65536
    float* fencs = ws + 131072;               // 65536
    float* h2s   = ws + 196608;               // 65536
    float* pmax  = ws + 262144;               // 50048
    float* psum  = ws + 312192;               // 50048
    float* pick  = ws + 362240;               // 128
    float* lp    = ws + 362368;               // 128
    float* qsc   = ws + 362496;               // 1024
    float* wmsc  = ws + 363520;               // 512
    float* wosc  = ws + 364032;               // 50048
    int8_t*   q8   = (int8_t*)(ws + 414080);  // 512 KB
    int8_t*   wmq  = (int8_t*)(ws + 545152);  // 512 KB
    int8_t*   chq  = (int8_t*)(ws + 676224);  // 128 KB
    int8_t*   mq   = (int8_t*)(ws + 708992);  // 64 KB
    uint32_t* woq2 = (uint32_t*)(ws + 725376);// 391*16384 u32 = 25.6 MB (padded)

    k_prep<<<dim3(384 + WO_BLK + 256), dim3(256), 0, stream>>>(
        Whh_e, Whh_d, Wm, Wo, fnums, enums, emb_f, emb_d, Wih_e, Wih_d, b_e, b_d,
        q8, qsc, wmq, wmsc, woq2, wosc, pre_e, pre_d);
    k_scan<<<dim3(2), dim3(1024), 0, stream>>>(q8, qsc, pre_e, pre_d, h0_e, h0_d, fencs, h2s);
    k_att1<<<dim3(NSTEP), dim3(512), 0, stream>>>(fencs, h2s, chq);
    k_att2<<<dim3(4), dim3(512), 0, stream>>>(chq, wmq, wmsc, bm, mq);
    k_logits<<<dim3(NBV), dim3(512), 0, stream>>>(mq, woq2, wosc, bo, enums, pmax, psum, pick);
    k_final_par<<<dim3(NSTEP), dim3(256), 0, stream>>>(pmax, psum, pick, lp);
    k_final_sum<<<dim3(1), dim3(NSTEP), 0, stream>>>(lp, (float*)d_out);
}

// Round 13
// 371.918 us; speedup vs baseline: 1.4890x; 1.1156x over previous
//
#include <hip/hip_runtime.h>
#include <stdint.h>

#define D      512
#define NSTEP  128          // SRC steps == decoder steps (TGT-1)
#define EVOC   50000
#define VTILE  128
#define NBV    ((EVOC + VTILE - 1) / VTILE)   // 391
#define LDA_W  36           // A LDS row stride in u32 words (144 B, 16B-aligned)
#define LDB_W  132          // B LDS kw-row stride in u32 words (16B-aligned)
#define WM16   (D / 16)                        // 32 Wm-quant helper blocks
#define WO16   ((EVOC + 15) / 16)              // 3125 Wo-quant helper blocks

typedef unsigned int u32x4 __attribute__((ext_vector_type(4)));

// ---- int8 dot4 (v_dot4_i32_i8) ----
__device__ inline int sdot4(int a, int b, int c) {
#if __has_builtin(__builtin_amdgcn_sdot4)
    return __builtin_amdgcn_sdot4(a, b, c, false);
#else
    int r = c;
    r += (int)(int8_t)(a)       * (int)(int8_t)(b);
    r += (int)(int8_t)(a >> 8)  * (int)(int8_t)(b >> 8);
    r += (int)(int8_t)(a >> 16) * (int)(int8_t)(b >> 16);
    r += (int)(int8_t)(a >> 24) * (int)(int8_t)(b >> 24);
    return r;
#endif
}

__device__ inline uint32_t pack4(float a, float b, float c, float d, float inv) {
    return  ((uint32_t)(uint8_t)(int8_t)__float2int_rn(a * inv)) |
            ((uint32_t)(uint8_t)(int8_t)__float2int_rn(b * inv) << 8) |
            ((uint32_t)(uint8_t)(int8_t)__float2int_rn(c * inv) << 16) |
            ((uint32_t)(uint8_t)(int8_t)__float2int_rn(d * inv) << 24);
}

__device__ inline float amax4(float4 v) {
    return fmaxf(fmaxf(fabsf(v.x), fabsf(v.y)), fmaxf(fabsf(v.z), fabsf(v.w)));
}

// ---- K_PREP2: only what the scan needs: Whh INT4 quant + pre matvec ----
// int4 packing (validated rounds 9/10, absmax 0.0): word j covers cols 8j..8j+7
// of a row; byte b = q[8j+b]&0xF | (q[8j+b+4]&0xF)<<4. Consumer: (w<<4)&M and
// w&M give the signed nibbles *16 exactly; one exact >>4 after accumulation.
__global__ __launch_bounds__(256) void k_prep2(
        const float* __restrict__ We,   const float* __restrict__ Wd,
        const int* __restrict__ fnums,  const int* __restrict__ enums,
        const float* __restrict__ emb_f,const float* __restrict__ emb_d,
        const float* __restrict__ Wih_e,const float* __restrict__ Wih_d,
        const float* __restrict__ b_e,  const float* __restrict__ b_d,
        uint32_t* __restrict__ q4, float* __restrict__ qsc,
        float* __restrict__ pre_e, float* __restrict__ pre_d) {
    __shared__ float xl[D];
    int bid = blockIdx.x, t = threadIdx.x;
    if (bid < 256) {                       // --- Whh int4 quant, 4 rows/block ---
        int rg = bid * 4 + (t >> 6);       // 0..1023
        int which = rg >> 9, row = rg & 511;
        int lane = t & 63;                 // word j = lane, cols 8j..8j+7
        const float* W = which ? Wd : We;
        const float* src = W + (size_t)row * D + lane * 8;
        float w[8];
        #pragma unroll
        for (int k = 0; k < 8; k++) w[k] = src[k];
        float m = 0.f;
        #pragma unroll
        for (int k = 0; k < 8; k++) m = fmaxf(m, fabsf(w[k]));
        for (int off = 32; off; off >>= 1) m = fmaxf(m, __shfl_xor(m, off));
        float inv = (m > 0.f) ? 7.f / m : 0.f;
        uint32_t word = 0;
        #pragma unroll
        for (int b = 0; b < 4; b++) {
            int qlo = max(-7, min(7, __float2int_rn(w[b] * inv)));
            int qhi = max(-7, min(7, __float2int_rn(w[b + 4] * inv)));
            word |= (((uint32_t)(qlo & 0xF)) | ((uint32_t)(qhi & 0xF) << 4)) << (8 * b);
        }
        q4[(size_t)which * 32768 + (size_t)row * 64 + lane] = word;
        if (lane == 0) qsc[which * D + row] = m / 7.f;
    } else {                               // --- pre matvec (256 blocks) ---
        int bb = bid - 256;
        int kind = bb >> 7, s = bb & 127;
        const float* emb = kind ? emb_d : emb_f;
        int idx          = kind ? enums[s] : fnums[s];
        const float* W   = kind ? Wih_d : Wih_e;
        const float* b   = kind ? b_d : b_e;
        float* pre       = kind ? pre_d : pre_e;
        xl[t]       = emb[(size_t)idx * D + t];
        xl[t + 256] = emb[(size_t)idx * D + t + 256];
        __syncthreads();
        for (int rep = 0; rep < 2; rep++) {
            int o = t + rep * 256;
            float acc = b[o];
            const float4* Wr = (const float4*)(W + (size_t)o * D);
            #pragma unroll 8
            for (int k4 = 0; k4 < D / 4; k4++) {
                float4 w = Wr[k4];
                acc += w.x * xl[4*k4] + w.y * xl[4*k4+1] + w.z * xl[4*k4+2] + w.w * xl[4*k4+3];
            }
            pre[(size_t)s * D + o] = acc;
        }
    }
}

// ---- K2 (fused): blocks 0-1 = the two sequential scans (int4 L2 stream,
// half the bytes of the 184us int8 roofline); blocks 2+ = Wm/Wo quantization
// running CONCURRENTLY on the 254 otherwise-idle CUs. ----
__global__ __launch_bounds__(1024)
__attribute__((amdgpu_waves_per_eu(4, 4)))
void k_scan_fused(
        const uint32_t* __restrict__ q4, const float* __restrict__ qsc,
        const float* __restrict__ pre_e, const float* __restrict__ pre_d,
        const float* __restrict__ h0_e, const float* __restrict__ h0_d,
        float* __restrict__ fencs, float* __restrict__ h2s,
        const float* __restrict__ Wm, const float* __restrict__ Wo,
        int8_t* __restrict__ wmq, float* __restrict__ wmsc,
        uint32_t* __restrict__ woq2, float* __restrict__ wosc) {
    __shared__ __align__(16) int8_t hq[2][D];
    int bid = blockIdx.x, t = threadIdx.x;

    if (bid >= 2) {
        int lane = t & 63, sub = t >> 6;           // 16 rows/block, 64 lanes/row
        if (bid < 2 + WM16) {                      // --- Wm int8 quant ---
            int row = (bid - 2) * 16 + sub;        // 0..511
            const float4* src = (const float4*)(Wm + (size_t)row * 2 * D);
            float4 a = src[lane], b = src[lane + 64], c = src[lane + 128], d2 = src[lane + 192];
            float m = fmaxf(fmaxf(amax4(a), amax4(b)), fmaxf(amax4(c), amax4(d2)));
            for (int off = 32; off; off >>= 1) m = fmaxf(m, __shfl_xor(m, off));
            float inv = (m > 0.f) ? 127.f / m : 0.f;
            uint32_t* dst = (uint32_t*)(wmq + (size_t)row * 2 * D);
            dst[lane]       = pack4(a.x, a.y, a.z, a.w, inv);
            dst[lane + 64]  = pack4(b.x, b.y, b.z, b.w, inv);
            dst[lane + 128] = pack4(c.x, c.y, c.z, c.w, inv);
            dst[lane + 192] = pack4(d2.x, d2.y, d2.z, d2.w, inv);
            if (lane == 0) wmsc[row] = m / 127.f;
        } else {                                   // --- Wo int8 quant -> woq2 ---
            int row = (bid - 2 - WM16) * 16 + sub;
            if (row < EVOC) {
                const float4* src = (const float4*)(Wo + (size_t)row * D);
                float4 v0 = src[lane], v1 = src[lane + 64];
                float m = fmaxf(amax4(v0), amax4(v1));
                for (int off = 32; off; off >>= 1) m = fmaxf(m, __shfl_xor(m, off));
                float inv = (m > 0.f) ? 127.f / m : 0.f;
                uint32_t w1 = pack4(v0.x, v0.y, v0.z, v0.w, inv);
                uint32_t w2 = pack4(v1.x, v1.y, v1.z, v1.w, inv);
                int wA = lane, wB = lane + 64;
                woq2[((size_t)(row >> 7) * 4 + (wA >> 5)) * 4096 + (size_t)(row & 127) * 32 + (wA & 31)] = w1;
                woq2[((size_t)(row >> 7) * 4 + (wB >> 5)) * 4096 + (size_t)(row & 127) * 32 + (wB & 31)] = w2;
                if (lane == 0) wosc[row] = m / 127.f;
            }
        }
        return;
    }

    // ---- scan path (blocks 0,1) ----
    int r = t >> 1, hf = t & 1;
    int which = bid;
    const float* pre = which ? pre_d : pre_e;
    const float* h0  = which ? h0_d : h0_e;
    float*       hs  = which ? h2s : fencs;
    float sw = qsc[which * D + r] * (1.f / 127.f);

    // 256 int4 weights/lane = 128 B = 8 named 128-bit regs (32 VGPRs)
    const u32x4* wr = (const u32x4*)(q4 + (size_t)which * 32768 + (size_t)r * 64 + hf * 32);
    u32x4 q0 = wr[0], q1 = wr[1], q2 = wr[2], q3 = wr[3];
    u32x4 q4v = wr[4], q5 = wr[5], q6 = wr[6], q7 = wr[7];

    if (hf == 0) {
        float h0v = fminf(fmaxf(h0[r], -0.999f), 0.999f);
        hq[0][r] = (int8_t)__float2int_rn(h0v * 127.f);
    }
    __syncthreads();

    const uint32_t M = 0xF0F0F0F0u;
    int p = 0;
    for (int step = 0; step < NSTEP; step++) {
        asm volatile("" : "+v"(q0), "+v"(q1), "+v"(q2), "+v"(q3),
                          "+v"(q4v),"+v"(q5), "+v"(q6), "+v"(q7));
        float prev = pre[(size_t)step * D + r];
        const u32x4* hv = (const u32x4*)(&hq[p][hf * 256]);
        int a0 = 0, a1 = 0, a2 = 0, a3 = 0;
        #define DOT4Q(i, qv) { u32x4 hA = hv[2*(i)], hB = hv[2*(i)+1];          \
            a0 = sdot4((int)(((qv).x << 4) & M), (int)hA.x, a0);                \
            a1 = sdot4((int)( (qv).x        & M), (int)hA.y, a1);               \
            a2 = sdot4((int)(((qv).y << 4) & M), (int)hA.z, a2);                \
            a3 = sdot4((int)( (qv).y        & M), (int)hA.w, a3);               \
            a0 = sdot4((int)(((qv).z << 4) & M), (int)hB.x, a0);                \
            a1 = sdot4((int)( (qv).z        & M), (int)hB.y, a1);               \
            a2 = sdot4((int)(((qv).w << 4) & M), (int)hB.z, a2);                \
            a3 = sdot4((int)( (qv).w        & M), (int)hB.w, a3); }
        DOT4Q(0, q0) DOT4Q(1, q1) DOT4Q(2, q2) DOT4Q(3, q3)
        DOT4Q(4, q4v) DOT4Q(5, q5) DOT4Q(6, q6) DOT4Q(7, q7)
        #undef DOT4Q
        int acc = (a0 + a1) + (a2 + a3);
        acc += __shfl_xor(acc, 1);                 // combine half-rows
        acc >>= 4;                                 // exact: every term is q*16*h
        if (hf == 0) {
            float h2 = tanhf(prev + (float)acc * sw);
            hs[(size_t)step * D + r] = h2;
            hq[p ^ 1][r] = (int8_t)__float2int_rn(h2 * 127.f);
        }
        p ^= 1;
        __syncthreads();
    }
}

// ---- K3a: attention scores + softmax + context -> chq = int8 [c | h2] ----
__global__ __launch_bounds__(512) void k_att1(
        const float* __restrict__ fencs, const float* __restrict__ h2s,
        int8_t* __restrict__ chq) {
    __shared__ float h2l[D], sc[NSTEP], red[64];
    __shared__ float ftile[32 * D];
    int s = blockIdx.x, t = threadIdx.x;
    h2l[t] = h2s[(size_t)s * D + t];
    __syncthreads();

    {   // scores[j] = fencs[j] . h2 ; thread (j = t>>2, q = t&3)
        int j = t >> 2, q = t & 3;
        const float4* fr = (const float4*)(fencs + (size_t)j * D + q * 128);
        const float4* hr = (const float4*)(h2l + q * 128);
        float acc = 0.f;
        #pragma unroll 8
        for (int k4 = 0; k4 < 32; k4++) {
            float4 f = fr[k4], hh = hr[k4];
            acc += f.x*hh.x + f.y*hh.y + f.z*hh.z + f.w*hh.w;
        }
        acc += __shfl_xor(acc, 1);
        acc += __shfl_xor(acc, 2);
        if (q == 0) sc[j] = acc;
    }
    __syncthreads();
    if (t < 64) {
        float m = fmaxf(sc[t], sc[t + 64]);
        for (int off = 32; off; off >>= 1) m = fmaxf(m, __shfl_xor(m, off));
        if (t == 0) red[0] = m;
    }
    __syncthreads();
    float mx = red[0];
    __syncthreads();
    if (t < NSTEP) sc[t] = expf(sc[t] - mx);
    __syncthreads();
    if (t < 64) {
        float v = sc[t] + sc[t + 64];
        for (int off = 32; off; off >>= 1) v += __shfl_xor(v, off);
        if (t == 0) red[0] = v;
    }
    __syncthreads();
    float inv = 1.0f / red[0];

    float cacc = 0.f;
    for (int jt = 0; jt < 4; jt++) {
        #pragma unroll
        for (int k = 0; k < 32; k++)
            ftile[t + k * D] = fencs[(size_t)jt * 32 * D + t + k * D];
        __syncthreads();
        #pragma unroll 8
        for (int j = 0; j < 32; j++)
            cacc += sc[jt * 32 + j] * ftile[j * D + t];
        __syncthreads();
    }
    float cv = cacc * inv;
    chq[(size_t)s * 2 * D + t]     = (int8_t)__float2int_rn(cv * 127.f);
    chq[(size_t)s * 2 * D + D + t] = (int8_t)__float2int_rn(h2l[t] * 127.f);
}

// ---- K3b: m = tanh([c,h2] @ Wm^T + bm) as ONE int8 GEMM (Wm read once) ----
__global__ __launch_bounds__(512) void k_att2(
        const int8_t* __restrict__ chq, const int8_t* __restrict__ wmq,
        const float* __restrict__ wmsc, const float* __restrict__ bm,
        int8_t* __restrict__ mq) {
    __shared__ __align__(16) uint32_t a_s[128 * LDA_W];
    __shared__ __align__(16) uint32_t b_s[32 * LDB_W];
    int t = threadIdx.x;
    int v0 = blockIdx.x * VTILE;
    int ti = t >> 5, tj = t & 31;
    int lrow = t >> 3, lq = t & 7;
    int acc[8][4] = {};

    for (int kc = 0; kc < 8; kc++) {
        #pragma unroll
        for (int rep = 0; rep < 2; rep++) {
            int row = lrow + rep * 64;
            uint4 av = *(const uint4*)(chq + (size_t)row * 2 * D + kc * 128 + lq * 16);
            *(uint4*)&a_s[row * LDA_W + lq * 4] = av;
            int v = v0 + row;
            uint4 bv = *(const uint4*)(wmq + (size_t)v * 2 * D + kc * 128 + lq * 16);
            b_s[(lq*4+0) * LDB_W + row] = bv.x;
            b_s[(lq*4+1) * LDB_W + row] = bv.y;
            b_s[(lq*4+2) * LDB_W + row] = bv.z;
            b_s[(lq*4+3) * LDB_W + row] = bv.w;
        }
        __syncthreads();
        #pragma unroll
        for (int q = 0; q < 8; q++) {
            uint4 aw[8];
            #pragma unroll
            for (int i = 0; i < 8; i++)
                aw[i] = *(const uint4*)&a_s[(ti*8 + i) * LDA_W + q*4];
            #pragma unroll
            for (int k4 = 0; k4 < 4; k4++) {
                uint4 bw = *(const uint4*)&b_s[(q*4 + k4) * LDB_W + tj * 4];
                #pragma unroll
                for (int i = 0; i < 8; i++) {
                    uint32_t a = (k4 == 0) ? aw[i].x : (k4 == 1) ? aw[i].y
                               : (k4 == 2) ? aw[i].z : aw[i].w;
                    acc[i][0] = sdot4((int)a, (int)bw.x, acc[i][0]);
                    acc[i][1] = sdot4((int)a, (int)bw.y, acc[i][1]);
                    acc[i][2] = sdot4((int)a, (int)bw.z, acc[i][2]);
                    acc[i][3] = sdot4((int)a, (int)bw.w, acc[i][3]);
                }
            }
        }
        __syncthreads();
    }

    float sw4[4], bm4[4];
    #pragma unroll
    for (int jj = 0; jj < 4; jj++) {
        int col = v0 + tj * 4 + jj;
        sw4[jj] = wmsc[col] * (1.f / (127.f * 127.f));
        bm4[jj] = bm[col];
    }
    #pragma unroll
    for (int i = 0; i < 8; i++) {
        int s = ti * 8 + i;
        float m0 = tanhf((float)acc[i][0] * sw4[0] + bm4[0]);
        float m1 = tanhf((float)acc[i][1] * sw4[1] + bm4[1]);
        float m2 = tanhf((float)acc[i][2] * sw4[2] + bm4[2]);
        float m3 = tanhf((float)acc[i][3] * sw4[3] + bm4[3]);
        ((uint32_t*)mq)[(size_t)s * (D / 4) + (v0 >> 2) + tj] = pack4(m0, m1, m2, m3, 127.f);
    }
}

// ---- K4: int8 logits GEMM + fused row max/sumexp ----
__global__ __launch_bounds__(512) void k_logits(
        const int8_t* __restrict__ mq, const uint32_t* __restrict__ woq2,
        const float* __restrict__ wosc, const float* __restrict__ bo,
        const int* __restrict__ enums,
        float* __restrict__ pmax, float* __restrict__ psum, float* __restrict__ pick) {
    __shared__ __align__(16) uint32_t a_s[128 * LDA_W];
    __shared__ __align__(16) uint32_t b_s[32 * LDB_W];
    int b = blockIdx.x, t = threadIdx.x;
    int v0 = b * VTILE;
    int ti = t >> 5, tj = t & 31;
    int lrow = t >> 3, lq = t & 7;
    int acc[8][4] = {};

    for (int kc = 0; kc < 4; kc++) {
        const uint4* bsrc = (const uint4*)(woq2 + ((size_t)b * 4 + kc) * 4096);
        #pragma unroll
        for (int rep = 0; rep < 2; rep++) {
            int row = lrow + rep * 64;
            uint4 av = *(const uint4*)(mq + (size_t)row * D + kc * 128 + lq * 16);
            *(uint4*)&a_s[row * LDA_W + lq * 4] = av;
            uint4 bv = bsrc[t + rep * 512];
            b_s[(lq*4+0) * LDB_W + row] = bv.x;
            b_s[(lq*4+1) * LDB_W + row] = bv.y;
            b_s[(lq*4+2) * LDB_W + row] = bv.z;
            b_s[(lq*4+3) * LDB_W + row] = bv.w;
        }
        __syncthreads();
        #pragma unroll
        for (int q = 0; q < 8; q++) {
            uint4 aw[8];
            #pragma unroll
            for (int i = 0; i < 8; i++)
                aw[i] = *(const uint4*)&a_s[(ti*8 + i) * LDA_W + q*4];
            #pragma unroll
            for (int k4 = 0; k4 < 4; k4++) {
                uint4 bw = *(const uint4*)&b_s[(q*4 + k4) * LDB_W + tj * 4];
                #pragma unroll
                for (int i = 0; i < 8; i++) {
                    uint32_t a = (k4 == 0) ? aw[i].x : (k4 == 1) ? aw[i].y
                               : (k4 == 2) ? aw[i].z : aw[i].w;
                    acc[i][0] = sdot4((int)a, (int)bw.x, acc[i][0]);
                    acc[i][1] = sdot4((int)a, (int)bw.y, acc[i][1]);
                    acc[i][2] = sdot4((int)a, (int)bw.z, acc[i][2]);
                    acc[i][3] = sdot4((int)a, (int)bw.w, acc[i][3]);
                }
            }
        }
        __syncthreads();
    }

    float sw4[4], bo4[4];
    int vld[4];
    #pragma unroll
    for (int jj = 0; jj < 4; jj++) {
        int v = v0 + tj * 4 + jj;
        vld[jj] = (v < EVOC);
        sw4[jj] = vld[jj] ? wosc[v] * (1.f / 127.f) : 0.f;
        bo4[jj] = vld[jj] ? bo[v] : 0.f;
    }
    #pragma unroll
    for (int i = 0; i < 8; i++) {
        int s = ti * 8 + i;
        float l[4];
        float mx = -1e30f;
        #pragma unroll
        for (int jj = 0; jj < 4; jj++) {
            l[jj] = vld[jj] ? (float)acc[i][jj] * sw4[jj] + bo4[jj] : -1e30f;
            mx = fmaxf(mx, l[jj]);
        }
        #pragma unroll
        for (int off = 1; off < 32; off <<= 1) mx = fmaxf(mx, __shfl_xor(mx, off));
        float sm = 0.f;
        #pragma unroll
        for (int jj = 0; jj < 4; jj++)
            if (vld[jj]) sm += expf(l[jj] - mx);
        #pragma unroll
        for (int off = 1; off < 32; off <<= 1) sm += __shfl_xor(sm, off);
        if (tj == 0) { pmax[b * NSTEP + s] = mx; psum[b * NSTEP + s] = sm; }
        int tgt = enums[s + 1];
        if (tgt >= v0 && tgt < v0 + VTILE) {
            int c = tgt - v0;
            if ((c >> 2) == tj) pick[s] = l[c & 3];
        }
    }
}

// ---- K5a: per-step logsumexp combine, 128 blocks in parallel ----
__global__ __launch_bounds__(256) void k_final_par(
        const float* __restrict__ pmax, const float* __restrict__ psum,
        const float* __restrict__ pick, float* __restrict__ lp) {
    __shared__ float red[8];
    int s = blockIdx.x, t = threadIdx.x;
    float M = -1e30f;
    for (int b = t; b < NBV; b += 256) M = fmaxf(M, pmax[b * NSTEP + s]);
    for (int off = 32; off; off >>= 1) M = fmaxf(M, __shfl_xor(M, off));
    if ((t & 63) == 0) red[t >> 6] = M;
    __syncthreads();
    M = fmaxf(fmaxf(red[0], red[1]), fmaxf(red[2], red[3]));
    float S = 0.f;
    for (int b = t; b < NBV; b += 256) S += psum[b * NSTEP + s] * expf(pmax[b * NSTEP + s] - M);
    for (int off = 32; off; off >>= 1) S += __shfl_xor(S, off);
    if ((t & 63) == 0) red[4 + (t >> 6)] = S;
    __syncthreads();
    if (t == 0) {
        S = red[4] + red[5] + red[6] + red[7];
        lp[s] = pick[s] - (M + logf(S));
    }
}

// ---- K5b: sum 128 logprobs ----
__global__ void k_final_sum(const float* __restrict__ lp, float* __restrict__ out) {
    __shared__ float red[NSTEP];
    int t = threadIdx.x;
    red[t] = lp[t];
    __syncthreads();
    for (int off = 64; off > 0; off >>= 1) {
        if (t < off) red[t] += red[t + off];
        __syncthreads();
    }
    if (t == 0) out[0] = red[0];
}

extern "C" void kernel_launch(void* const* d_in, const int* in_sizes, int n_in,
                              void* d_out, int out_size, void* d_ws, size_t ws_size,
                              hipStream_t stream) {
    const int*   fnums = (const int*)  d_in[0];
    const int*   enums = (const int*)  d_in[1];
    const float* emb_f = (const float*)d_in[2];
    const float* Wih_e = (const float*)d_in[3];
    const float* Whh_e = (const float*)d_in[4];
    const float* b_e   = (const float*)d_in[5];
    const float* h0_e  = (const float*)d_in[6];
    const float* emb_d = (const float*)d_in[7];
    const float* Wih_d = (const float*)d_in[8];
    const float* Whh_d = (const float*)d_in[9];
    const float* b_d   = (const float*)d_in[10];
    const float* h0_d  = (const float*)d_in[11];
    const float* Wm    = (const float*)d_in[12];
    const float* bm    = (const float*)d_in[13];
    const float* Wo    = (const float*)d_in[14];
    const float* bo    = (const float*)d_in[15];

    float* ws = (float*)d_ws;
    float* pre_e = ws;                        // 65536
    float* pre_d = ws + 65536;                // 65536
    float* fencs = ws + 131072;               // 65536
    float* h2s   = ws + 196608;               // 65536
    float* pmax  = ws + 262144;               // 50048
    float* psum  = ws + 312192;               // 50048
    float* pick  = ws + 362240;               // 128
    float* lp    = ws + 362368;               // 128
    float* qsc   = ws + 362496;               // 1024
    float* wmsc  = ws + 363520;               // 512
    float* wosc  = ws + 364032;               // 50048
    uint32_t* q4 = (uint32_t*)(ws + 414080);  // 65536 u32 = 256 KB int4 scan weights
    int8_t*   wmq  = (int8_t*)(ws + 479616);  // 512 KB
    int8_t*   chq  = (int8_t*)(ws + 610688);  // 128 KB
    int8_t*   mq   = (int8_t*)(ws + 643456);  // 64 KB
    uint32_t* woq2 = (uint32_t*)(ws + 659840);// 391*16384 u32 = 25.6 MB (padded)

    k_prep2<<<dim3(512), dim3(256), 0, stream>>>(
        Whh_e, Whh_d, fnums, enums, emb_f, emb_d, Wih_e, Wih_d, b_e, b_d,
        q4, qsc, pre_e, pre_d);
    k_scan_fused<<<dim3(2 + WM16 + WO16), dim3(1024), 0, stream>>>(
        q4, qsc, pre_e, pre_d, h0_e, h0_d, fencs, h2s,
        Wm, Wo, wmq, wmsc, woq2, wosc);
    k_att1<<<dim3(NSTEP), dim3(512), 0, stream>>>(fencs, h2s, chq);
    k_att2<<<dim3(4), dim3(512), 0, stream>>>(chq, wmq, wmsc, bm, mq);
    k_logits<<<dim3(NBV), dim3(512), 0, stream>>>(mq, woq2, wosc, bo, enums, pmax, psum, pick);
    k_final_par<<<dim3(NSTEP), dim3(256), 0, stream>>>(pmax, psum, pick, lp);
    k_final_sum<<<dim3(1), dim3(NSTEP), 0, stream>>>(lp, (float*)d_out);
}

// Round 14
// 319.179 us; speedup vs baseline: 1.7350x; 1.1652x over previous
//
#include <hip/hip_runtime.h>
#include <stdint.h>

#define D      512
#define NSTEP  128          // SRC steps == decoder steps (TGT-1)
#define EVOC   50000
#define VTILE  128
#define NBV    ((EVOC + VTILE - 1) / VTILE)   // 391
#define LDA_W  36           // A LDS row stride in u32 words (144 B, 16B-aligned)
#define LDB_W  132          // B LDS kw-row stride in u32 words (16B-aligned)
#define WM16   (D / 16)                        // 32 Wm-quant helper blocks
#define WO16   ((EVOC + 15) / 16)              // 3125 Wo-quant helper blocks

typedef unsigned int u32x4 __attribute__((ext_vector_type(4)));

// ---- int8 dot4 (v_dot4_i32_i8) ----
__device__ inline int sdot4(int a, int b, int c) {
#if __has_builtin(__builtin_amdgcn_sdot4)
    return __builtin_amdgcn_sdot4(a, b, c, false);
#else
    int r = c;
    r += (int)(int8_t)(a)       * (int)(int8_t)(b);
    r += (int)(int8_t)(a >> 8)  * (int)(int8_t)(b >> 8);
    r += (int)(int8_t)(a >> 16) * (int)(int8_t)(b >> 16);
    r += (int)(int8_t)(a >> 24) * (int)(int8_t)(b >> 24);
    return r;
#endif
}

__device__ inline int rdlane(uint32_t v, int k) {
#if __has_builtin(__builtin_amdgcn_readlane)
    return (int)__builtin_amdgcn_readlane(v, k);
#else
    return (int)__shfl((int)v, k, 64);
#endif
}

__device__ inline uint32_t pack4(float a, float b, float c, float d, float inv) {
    return  ((uint32_t)(uint8_t)(int8_t)__float2int_rn(a * inv)) |
            ((uint32_t)(uint8_t)(int8_t)__float2int_rn(b * inv) << 8) |
            ((uint32_t)(uint8_t)(int8_t)__float2int_rn(c * inv) << 16) |
            ((uint32_t)(uint8_t)(int8_t)__float2int_rn(d * inv) << 24);
}

__device__ inline float amax4(float4 v) {
    return fmaxf(fmaxf(fabsf(v.x), fabsf(v.y)), fmaxf(fabsf(v.z), fabsf(v.w)));
}

// ---- K_PREP2: Whh INT4 quant (chunked layout) + pre matvec ----
// int4 packing (validated): word covers 8 cols; byte b = q[+b]&0xF | (q[+b+4]&0xF)<<4.
// ((w<<4)&M) = cols +0..3 *16 signed exact; (w&M) = cols +4..7 *16. One exact >>4.
// Chunked layout for the scan's coalesced stream: u32x4 chunk index =
// which*8192 + c*1024 + scan_thread, scan_thread = (hf<<9)|row, chunk c covers
// cols hf*256 + c*32 + [0..32).
__global__ __launch_bounds__(256) void k_prep2(
        const float* __restrict__ We,   const float* __restrict__ Wd,
        const int* __restrict__ fnums,  const int* __restrict__ enums,
        const float* __restrict__ emb_f,const float* __restrict__ emb_d,
        const float* __restrict__ Wih_e,const float* __restrict__ Wih_d,
        const float* __restrict__ b_e,  const float* __restrict__ b_d,
        uint32_t* __restrict__ q4, float* __restrict__ qsc,
        float* __restrict__ pre_e, float* __restrict__ pre_d) {
    __shared__ float xl[D];
    int bid = blockIdx.x, t = threadIdx.x;
    if (bid < 256) {                       // --- Whh int4 quant, 4 rows/block ---
        int rg = bid * 4 + (t >> 6);       // 0..1023
        int which = rg >> 9, row = rg & 511;
        int lane = t & 63;                 // word index: cols 8*lane..8*lane+7
        const float* W = which ? Wd : We;
        const float* src = W + (size_t)row * D + lane * 8;
        float w[8];
        #pragma unroll
        for (int k = 0; k < 8; k++) w[k] = src[k];
        float m = 0.f;
        #pragma unroll
        for (int k = 0; k < 8; k++) m = fmaxf(m, fabsf(w[k]));
        for (int off = 32; off; off >>= 1) m = fmaxf(m, __shfl_xor(m, off));
        float inv = (m > 0.f) ? 7.f / m : 0.f;
        uint32_t word = 0;
        #pragma unroll
        for (int b = 0; b < 4; b++) {
            int qlo = max(-7, min(7, __float2int_rn(w[b] * inv)));
            int qhi = max(-7, min(7, __float2int_rn(w[b + 4] * inv)));
            word |= (((uint32_t)(qlo & 0xF)) | ((uint32_t)(qhi & 0xF) << 4)) << (8 * b);
        }
        int hf = lane >> 5, c = (lane & 31) >> 2, wi = lane & 3;
        q4[((size_t)which * 8192 + (size_t)c * 1024 + (hf << 9) + row) * 4 + wi] = word;
        if (lane == 0) qsc[which * D + row] = m / 7.f;
    } else {                               // --- pre matvec (256 blocks) ---
        int bb = bid - 256;
        int kind = bb >> 7, s = bb & 127;
        const float* emb = kind ? emb_d : emb_f;
        int idx          = kind ? enums[s] : fnums[s];
        const float* W   = kind ? Wih_d : Wih_e;
        const float* b   = kind ? b_d : b_e;
        float* pre       = kind ? pre_d : pre_e;
        xl[t]       = emb[(size_t)idx * D + t];
        xl[t + 256] = emb[(size_t)idx * D + t + 256];
        __syncthreads();
        for (int rep = 0; rep < 2; rep++) {
            int o = t + rep * 256;
            float acc = b[o];
            const float4* Wr = (const float4*)(W + (size_t)o * D);
            #pragma unroll 8
            for (int k4 = 0; k4 < D / 4; k4++) {
                float4 w = Wr[k4];
                acc += w.x * xl[4*k4] + w.y * xl[4*k4+1] + w.z * xl[4*k4+2] + w.w * xl[4*k4+3];
            }
            pre[(size_t)s * D + o] = acc;
        }
    }
}

// ---- K2 (fused): blocks 0-1 = scans; blocks 2+ = Wm/Wo quant on idle CUs. ----
// Scan redesign: hf = t>>9 is WAVE-UNIFORM; each lane reads ONE u32 of h
// (ds_read_b32) and the 64 half-row words are distributed via v_readlane
// (VALU) -- removes the 256 ds_read_b128/step h-broadcast (~3072 cyc) that
// was the binding pipe in every prior variant. Weights: int4 streamed from
// L2 (128 KB/step, ~1700 cyc) overlapping the ~2000 cyc VALU work.
__global__ __launch_bounds__(1024)
__attribute__((amdgpu_waves_per_eu(4, 4)))
void k_scan_fused(
        const uint32_t* __restrict__ q4, const float* __restrict__ qsc,
        const float* __restrict__ pre_e, const float* __restrict__ pre_d,
        const float* __restrict__ h0_e, const float* __restrict__ h0_d,
        float* __restrict__ fencs, float* __restrict__ h2s,
        const float* __restrict__ Wm, const float* __restrict__ Wo,
        int8_t* __restrict__ wmq, float* __restrict__ wmsc,
        uint32_t* __restrict__ woq2, float* __restrict__ wosc) {
    __shared__ __align__(16) uint32_t hq32[2][D / 4];   // int8 h, double-buffered
    __shared__ int pacc[D];                              // hf1 partial sums
    int bid = blockIdx.x, t = threadIdx.x;

    if (bid >= 2) {
        int lane = t & 63, sub = t >> 6;           // 16 rows/block, 64 lanes/row
        if (bid < 2 + WM16) {                      // --- Wm int8 quant ---
            int row = (bid - 2) * 16 + sub;        // 0..511
            const float4* src = (const float4*)(Wm + (size_t)row * 2 * D);
            float4 a = src[lane], b = src[lane + 64], c = src[lane + 128], d2 = src[lane + 192];
            float m = fmaxf(fmaxf(amax4(a), amax4(b)), fmaxf(amax4(c), amax4(d2)));
            for (int off = 32; off; off >>= 1) m = fmaxf(m, __shfl_xor(m, off));
            float inv = (m > 0.f) ? 127.f / m : 0.f;
            uint32_t* dst = (uint32_t*)(wmq + (size_t)row * 2 * D);
            dst[lane]       = pack4(a.x, a.y, a.z, a.w, inv);
            dst[lane + 64]  = pack4(b.x, b.y, b.z, b.w, inv);
            dst[lane + 128] = pack4(c.x, c.y, c.z, c.w, inv);
            dst[lane + 192] = pack4(d2.x, d2.y, d2.z, d2.w, inv);
            if (lane == 0) wmsc[row] = m / 127.f;
        } else {                                   // --- Wo int8 quant -> woq2 ---
            int row = (bid - 2 - WM16) * 16 + sub;
            if (row < EVOC) {
                const float4* src = (const float4*)(Wo + (size_t)row * D);
                float4 v0 = src[lane], v1 = src[lane + 64];
                float m = fmaxf(amax4(v0), amax4(v1));
                for (int off = 32; off; off >>= 1) m = fmaxf(m, __shfl_xor(m, off));
                float inv = (m > 0.f) ? 127.f / m : 0.f;
                uint32_t w1 = pack4(v0.x, v0.y, v0.z, v0.w, inv);
                uint32_t w2 = pack4(v1.x, v1.y, v1.z, v1.w, inv);
                int wA = lane, wB = lane + 64;
                woq2[((size_t)(row >> 7) * 4 + (wA >> 5)) * 4096 + (size_t)(row & 127) * 32 + (wA & 31)] = w1;
                woq2[((size_t)(row >> 7) * 4 + (wB >> 5)) * 4096 + (size_t)(row & 127) * 32 + (wB & 31)] = w2;
                if (lane == 0) wosc[row] = m / 127.f;
            }
        }
        return;
    }

    // ---- scan path (blocks 0,1) ----
    int lane = t & 63;
    int hf = t >> 9;                 // wave-uniform half selector
    int r  = t & 511;                // row
    int which = bid;
    const float* pre = which ? pre_d : pre_e;
    const float* h0  = which ? h0_d : h0_e;
    float*       hs  = which ? h2s : fencs;
    float sw = qsc[which * D + r] * (1.f / 127.f);
    const u32x4* wq = (const u32x4*)q4 + (size_t)which * 8192 + t;

    int8_t* hq8 = (int8_t*)hq32;
    if (hf == 0) {
        float h0v = fminf(fmaxf(h0[r], -0.999f), 0.999f);
        hq8[r] = (int8_t)__float2int_rn(h0v * 127.f);
    }
    __syncthreads();

    const uint32_t M = 0xF0F0F0F0u;
    int p = 0;
    for (int step = 0; step < NSTEP; step++) {
        uint32_t own = hq32[p][(hf << 6) | lane];  // one u32 of h per lane
        int a0 = 0, a1 = 0;
        #pragma unroll
        for (int c = 0; c < 8; c++) {
            u32x4 wv = wq[c * 1024];               // coalesced 16B/lane from L2
            #pragma unroll
            for (int wi = 0; wi < 4; wi++) {
                uint32_t w = wv[wi];
                int hA = rdlane(own, c * 8 + wi * 2);       // cols +0..3
                int hB = rdlane(own, c * 8 + wi * 2 + 1);   // cols +4..7
                a0 = sdot4((int)((w << 4) & M), hA, a0);
                a1 = sdot4((int)(w & M), hB, a1);
            }
        }
        int acc = a0 + a1;
        if (hf) pacc[r] = acc;
        __syncthreads();
        if (!hf) {
            int tot = (acc + pacc[r]) >> 4;        // exact: every term is q*16*h
            float h2 = tanhf(pre[(size_t)step * D + r] + (float)tot * sw);
            hs[(size_t)step * D + r] = h2;
            hq8[(p ^ 1) * D + r] = (int8_t)__float2int_rn(h2 * 127.f);
        }
        __syncthreads();
        p ^= 1;
    }
}

// ---- K3a: attention scores + softmax + context -> chq = int8 [c | h2] ----
__global__ __launch_bounds__(512) void k_att1(
        const float* __restrict__ fencs, const float* __restrict__ h2s,
        int8_t* __restrict__ chq) {
    __shared__ float h2l[D], sc[NSTEP], red[64];
    __shared__ float ftile[32 * D];
    int s = blockIdx.x, t = threadIdx.x;
    h2l[t] = h2s[(size_t)s * D + t];
    __syncthreads();

    {   // scores[j] = fencs[j] . h2 ; thread (j = t>>2, q = t&3)
        int j = t >> 2, q = t & 3;
        const float4* fr = (const float4*)(fencs + (size_t)j * D + q * 128);
        const float4* hr = (const float4*)(h2l + q * 128);
        float acc = 0.f;
        #pragma unroll 8
        for (int k4 = 0; k4 < 32; k4++) {
            float4 f = fr[k4], hh = hr[k4];
            acc += f.x*hh.x + f.y*hh.y + f.z*hh.z + f.w*hh.w;
        }
        acc += __shfl_xor(acc, 1);
        acc += __shfl_xor(acc, 2);
        if (q == 0) sc[j] = acc;
    }
    __syncthreads();
    if (t < 64) {
        float m = fmaxf(sc[t], sc[t + 64]);
        for (int off = 32; off; off >>= 1) m = fmaxf(m, __shfl_xor(m, off));
        if (t == 0) red[0] = m;
    }
    __syncthreads();
    float mx = red[0];
    __syncthreads();
    if (t < NSTEP) sc[t] = expf(sc[t] - mx);
    __syncthreads();
    if (t < 64) {
        float v = sc[t] + sc[t + 64];
        for (int off = 32; off; off >>= 1) v += __shfl_xor(v, off);
        if (t == 0) red[0] = v;
    }
    __syncthreads();
    float inv = 1.0f / red[0];

    float cacc = 0.f;
    for (int jt = 0; jt < 4; jt++) {
        #pragma unroll
        for (int k = 0; k < 32; k++)
            ftile[t + k * D] = fencs[(size_t)jt * 32 * D + t + k * D];
        __syncthreads();
        #pragma unroll 8
        for (int j = 0; j < 32; j++)
            cacc += sc[jt * 32 + j] * ftile[j * D + t];
        __syncthreads();
    }
    float cv = cacc * inv;
    chq[(size_t)s * 2 * D + t]     = (int8_t)__float2int_rn(cv * 127.f);
    chq[(size_t)s * 2 * D + D + t] = (int8_t)__float2int_rn(h2l[t] * 127.f);
}

// ---- K3b: m = tanh([c,h2] @ Wm^T + bm) as ONE int8 GEMM (Wm read once) ----
__global__ __launch_bounds__(512) void k_att2(
        const int8_t* __restrict__ chq, const int8_t* __restrict__ wmq,
        const float* __restrict__ wmsc, const float* __restrict__ bm,
        int8_t* __restrict__ mq) {
    __shared__ __align__(16) uint32_t a_s[128 * LDA_W];
    __shared__ __align__(16) uint32_t b_s[32 * LDB_W];
    int t = threadIdx.x;
    int v0 = blockIdx.x * VTILE;
    int ti = t >> 5, tj = t & 31;
    int lrow = t >> 3, lq = t & 7;
    int acc[8][4] = {};

    for (int kc = 0; kc < 8; kc++) {
        #pragma unroll
        for (int rep = 0; rep < 2; rep++) {
            int row = lrow + rep * 64;
            uint4 av = *(const uint4*)(chq + (size_t)row * 2 * D + kc * 128 + lq * 16);
            *(uint4*)&a_s[row * LDA_W + lq * 4] = av;
            int v = v0 + row;
            uint4 bv = *(const uint4*)(wmq + (size_t)v * 2 * D + kc * 128 + lq * 16);
            b_s[(lq*4+0) * LDB_W + row] = bv.x;
            b_s[(lq*4+1) * LDB_W + row] = bv.y;
            b_s[(lq*4+2) * LDB_W + row] = bv.z;
            b_s[(lq*4+3) * LDB_W + row] = bv.w;
        }
        __syncthreads();
        #pragma unroll
        for (int q = 0; q < 8; q++) {
            uint4 aw[8];
            #pragma unroll
            for (int i = 0; i < 8; i++)
                aw[i] = *(const uint4*)&a_s[(ti*8 + i) * LDA_W + q*4];
            #pragma unroll
            for (int k4 = 0; k4 < 4; k4++) {
                uint4 bw = *(const uint4*)&b_s[(q*4 + k4) * LDB_W + tj * 4];
                #pragma unroll
                for (int i = 0; i < 8; i++) {
                    uint32_t a = (k4 == 0) ? aw[i].x : (k4 == 1) ? aw[i].y
                               : (k4 == 2) ? aw[i].z : aw[i].w;
                    acc[i][0] = sdot4((int)a, (int)bw.x, acc[i][0]);
                    acc[i][1] = sdot4((int)a, (int)bw.y, acc[i][1]);
                    acc[i][2] = sdot4((int)a, (int)bw.z, acc[i][2]);
                    acc[i][3] = sdot4((int)a, (int)bw.w, acc[i][3]);
                }
            }
        }
        __syncthreads();
    }

    float sw4[4], bm4[4];
    #pragma unroll
    for (int jj = 0; jj < 4; jj++) {
        int col = v0 + tj * 4 + jj;
        sw4[jj] = wmsc[col] * (1.f / (127.f * 127.f));
        bm4[jj] = bm[col];
    }
    #pragma unroll
    for (int i = 0; i < 8; i++) {
        int s = ti * 8 + i;
        float m0 = tanhf((float)acc[i][0] * sw4[0] + bm4[0]);
        float m1 = tanhf((float)acc[i][1] * sw4[1] + bm4[1]);
        float m2 = tanhf((float)acc[i][2] * sw4[2] + bm4[2]);
        float m3 = tanhf((float)acc[i][3] * sw4[3] + bm4[3]);
        ((uint32_t*)mq)[(size_t)s * (D / 4) + (v0 >> 2) + tj] = pack4(m0, m1, m2, m3, 127.f);
    }
}

// ---- K4: int8 logits GEMM + fused row max/sumexp ----
__global__ __launch_bounds__(512) void k_logits(
        const int8_t* __restrict__ mq, const uint32_t* __restrict__ woq2,
        const float* __restrict__ wosc, const float* __restrict__ bo,
        const int* __restrict__ enums,
        float* __restrict__ pmax, float* __restrict__ psum, float* __restrict__ pick) {
    __shared__ __align__(16) uint32_t a_s[128 * LDA_W];
    __shared__ __align__(16) uint32_t b_s[32 * LDB_W];
    int b = blockIdx.x, t = threadIdx.x;
    int v0 = b * VTILE;
    int ti = t >> 5, tj = t & 31;
    int lrow = t >> 3, lq = t & 7;
    int acc[8][4] = {};

    for (int kc = 0; kc < 4; kc++) {
        const uint4* bsrc = (const uint4*)(woq2 + ((size_t)b * 4 + kc) * 4096);
        #pragma unroll
        for (int rep = 0; rep < 2; rep++) {
            int row = lrow + rep * 64;
            uint4 av = *(const uint4*)(mq + (size_t)row * D + kc * 128 + lq * 16);
            *(uint4*)&a_s[row * LDA_W + lq * 4] = av;
            uint4 bv = bsrc[t + rep * 512];
            b_s[(lq*4+0) * LDB_W + row] = bv.x;
            b_s[(lq*4+1) * LDB_W + row] = bv.y;
            b_s[(lq*4+2) * LDB_W + row] = bv.z;
            b_s[(lq*4+3) * LDB_W + row] = bv.w;
        }
        __syncthreads();
        #pragma unroll
        for (int q = 0; q < 8; q++) {
            uint4 aw[8];
            #pragma unroll
            for (int i = 0; i < 8; i++)
                aw[i] = *(const uint4*)&a_s[(ti*8 + i) * LDA_W + q*4];
            #pragma unroll
            for (int k4 = 0; k4 < 4; k4++) {
                uint4 bw = *(const uint4*)&b_s[(q*4 + k4) * LDB_W + tj * 4];
                #pragma unroll
                for (int i = 0; i < 8; i++) {
                    uint32_t a = (k4 == 0) ? aw[i].x : (k4 == 1) ? aw[i].y
                               : (k4 == 2) ? aw[i].z : aw[i].w;
                    acc[i][0] = sdot4((int)a, (int)bw.x, acc[i][0]);
                    acc[i][1] = sdot4((int)a, (int)bw.y, acc[i][1]);
                    acc[i][2] = sdot4((int)a, (int)bw.z, acc[i][2]);
                    acc[i][3] = sdot4((int)a, (int)bw.w, acc[i][3]);
                }
            }
        }
        __syncthreads();
    }

    float sw4[4], bo4[4];
    int vld[4];
    #pragma unroll
    for (int jj = 0; jj < 4; jj++) {
        int v = v0 + tj * 4 + jj;
        vld[jj] = (v < EVOC);
        sw4[jj] = vld[jj] ? wosc[v] * (1.f / 127.f) : 0.f;
        bo4[jj] = vld[jj] ? bo[v] : 0.f;
    }
    #pragma unroll
    for (int i = 0; i < 8; i++) {
        int s = ti * 8 + i;
        float l[4];
        float mx = -1e30f;
        #pragma unroll
        for (int jj = 0; jj < 4; jj++) {
            l[jj] = vld[jj] ? (float)acc[i][jj] * sw4[jj] + bo4[jj] : -1e30f;
            mx = fmaxf(mx, l[jj]);
        }
        #pragma unroll
        for (int off = 1; off < 32; off <<= 1) mx = fmaxf(mx, __shfl_xor(mx, off));
        float sm = 0.f;
        #pragma unroll
        for (int jj = 0; jj < 4; jj++)
            if (vld[jj]) sm += expf(l[jj] - mx);
        #pragma unroll
        for (int off = 1; off < 32; off <<= 1) sm += __shfl_xor(sm, off);
        if (tj == 0) { pmax[b * NSTEP + s] = mx; psum[b * NSTEP + s] = sm; }
        int tgt = enums[s + 1];
        if (tgt >= v0 && tgt < v0 + VTILE) {
            int c = tgt - v0;
            if ((c >> 2) == tj) pick[s] = l[c & 3];
        }
    }
}

// ---- K5a: per-step logsumexp combine, 128 blocks in parallel ----
__global__ __launch_bounds__(256) void k_final_par(
        const float* __restrict__ pmax, const float* __restrict__ psum,
        const float* __restrict__ pick, float* __restrict__ lp) {
    __shared__ float red[8];
    int s = blockIdx.x, t = threadIdx.x;
    float M = -1e30f;
    for (int b = t; b < NBV; b += 256) M = fmaxf(M, pmax[b * NSTEP + s]);
    for (int off = 32; off; off >>= 1) M = fmaxf(M, __shfl_xor(M, off));
    if ((t & 63) == 0) red[t >> 6] = M;
    __syncthreads();
    M = fmaxf(fmaxf(red[0], red[1]), fmaxf(red[2], red[3]));
    float S = 0.f;
    for (int b = t; b < NBV; b += 256) S += psum[b * NSTEP + s] * expf(pmax[b * NSTEP + s] - M);
    for (int off = 32; off; off >>= 1) S += __shfl_xor(S, off);
    if ((t & 63) == 0) red[4 + (t >> 6)] = S;
    __syncthreads();
    if (t == 0) {
        S = red[4] + red[5] + red[6] + red[7];
        lp[s] = pick[s] - (M + logf(S));
    }
}

// ---- K5b: sum 128 logprobs ----
__global__ void k_final_sum(const float* __restrict__ lp, float* __restrict__ out) {
    __shared__ float red[NSTEP];
    int t = threadIdx.x;
    red[t] = lp[t];
    __syncthreads();
    for (int off = 64; off > 0; off >>= 1) {
        if (t < off) red[t] += red[t + off];
        __syncthreads();
    }
    if (t == 0) out[0] = red[0];
}

extern "C" void kernel_launch(void* const* d_in, const int* in_sizes, int n_in,
                              void* d_out, int out_size, void* d_ws, size_t ws_size,
                              hipStream_t stream) {
    const int*   fnums = (const int*)  d_in[0];
    const int*   enums = (const int*)  d_in[1];
    const float* emb_f = (const float*)d_in[2];
    const float* Wih_e = (const float*)d_in[3];
    const float* Whh_e = (const float*)d_in[4];
    const float* b_e   = (const float*)d_in[5];
    const float* h0_e  = (const float*)d_in[6];
    const float* emb_d = (const float*)d_in[7];
    const float* Wih_d = (const float*)d_in[8];
    const float* Whh_d = (const float*)d_in[9];
    const float* b_d   = (const float*)d_in[10];
    const float* h0_d  = (const float*)d_in[11];
    const float* Wm    = (const float*)d_in[12];
    const float* bm    = (const float*)d_in[13];
    const float* Wo    = (const float*)d_in[14];
    const float* bo    = (const float*)d_in[15];

    float* ws = (float*)d_ws;
    float* pre_e = ws;                        // 65536
    float* pre_d = ws + 65536;                // 65536
    float* fencs = ws + 131072;               // 65536
    float* h2s   = ws + 196608;               // 65536
    float* pmax  = ws + 262144;               // 50048
    float* psum  = ws + 312192;               // 50048
    float* pick  = ws + 362240;               // 128
    float* lp    = ws + 362368;               // 128
    float* qsc   = ws + 362496;               // 1024
    float* wmsc  = ws + 363520;               // 512
    float* wosc  = ws + 364032;               // 50048
    uint32_t* q4 = (uint32_t*)(ws + 414080);  // 65536 u32 = 256 KB int4 scan weights
    int8_t*   wmq  = (int8_t*)(ws + 479616);  // 512 KB
    int8_t*   chq  = (int8_t*)(ws + 610688);  // 128 KB
    int8_t*   mq   = (int8_t*)(ws + 643456);  // 64 KB
    uint32_t* woq2 = (uint32_t*)(ws + 659840);// 391*16384 u32 = 25.6 MB (padded)

    k_prep2<<<dim3(512), dim3(256), 0, stream>>>(
        Whh_e, Whh_d, fnums, enums, emb_f, emb_d, Wih_e, Wih_d, b_e, b_d,
        q4, qsc, pre_e, pre_d);
    k_scan_fused<<<dim3(2 + WM16 + WO16), dim3(1024), 0, stream>>>(
        q4, qsc, pre_e, pre_d, h0_e, h0_d, fencs, h2s,
        Wm, Wo, wmq, wmsc, woq2, wosc);
    k_att1<<<dim3(NSTEP), dim3(512), 0, stream>>>(fencs, h2s, chq);
    k_att2<<<dim3(4), dim3(512), 0, stream>>>(chq, wmq, wmsc, bm, mq);
    k_logits<<<dim3(NBV), dim3(512), 0, stream>>>(mq, woq2, wosc, bo, enums, pmax, psum, pick);
    k_final_par<<<dim3(NSTEP), dim3(256), 0, stream>>>(pmax, psum, pick, lp);
    k_final_sum<<<dim3(1), dim3(NSTEP), 0, stream>>>(lp, (float*)d_out);
}

// Round 15
// 272.856 us; speedup vs baseline: 2.0296x; 1.1698x over previous
//
#include <hip/hip_runtime.h>
#include <stdint.h>

#define D      512
#define NSTEP  128          // SRC steps == decoder steps (TGT-1)
#define EVOC   50000
#define VTILE  128
#define NBV    ((EVOC + VTILE - 1) / VTILE)   // 391
#define LDA_W  36           // A LDS row stride in u32 words (144 B, 16B-aligned)
#define LDB_W  132          // B LDS kw-row stride in u32 words (16B-aligned)
#define WM16   (D / 16)                        // 32 Wm-quant helper blocks
#define WO16   ((EVOC + 15) / 16)              // 3125 Wo-quant helper blocks

typedef unsigned int u32x4 __attribute__((ext_vector_type(4)));

// ---- int8 dot4 (v_dot4_i32_i8) ----
__device__ inline int sdot4(int a, int b, int c) {
#if __has_builtin(__builtin_amdgcn_sdot4)
    return __builtin_amdgcn_sdot4(a, b, c, false);
#else
    int r = c;
    r += (int)(int8_t)(a)       * (int)(int8_t)(b);
    r += (int)(int8_t)(a >> 8)  * (int)(int8_t)(b >> 8);
    r += (int)(int8_t)(a >> 16) * (int)(int8_t)(b >> 16);
    r += (int)(int8_t)(a >> 24) * (int)(int8_t)(b >> 24);
    return r;
#endif
}

// ---- int4 dot8 (v_dot8_i32_i4): 8 signed-nibble MACs per instruction ----
__device__ inline int sdot8(uint32_t a, uint32_t b, int c) {
#if __has_builtin(__builtin_amdgcn_sdot8)
    return __builtin_amdgcn_sdot8((int)a, (int)b, c, false);
#else
    int r = c;
    #pragma unroll
    for (int k = 0; k < 8; k++) {
        int av = ((int)(a << (28 - 4 * k))) >> 28;
        int bv = ((int)(b << (28 - 4 * k))) >> 28;
        r += av * bv;
    }
    return r;
#endif
}

__device__ inline int rdlane(uint32_t v, int k) {
#if __has_builtin(__builtin_amdgcn_readlane)
    return (int)__builtin_amdgcn_readlane(v, k);
#else
    return (int)__shfl((int)v, k, 64);
#endif
}

__device__ inline uint32_t pack4(float a, float b, float c, float d, float inv) {
    return  ((uint32_t)(uint8_t)(int8_t)__float2int_rn(a * inv)) |
            ((uint32_t)(uint8_t)(int8_t)__float2int_rn(b * inv) << 8) |
            ((uint32_t)(uint8_t)(int8_t)__float2int_rn(c * inv) << 16) |
            ((uint32_t)(uint8_t)(int8_t)__float2int_rn(d * inv) << 24);
}

__device__ inline float amax4(float4 v) {
    return fmaxf(fmaxf(fabsf(v.x), fabsf(v.y)), fmaxf(fabsf(v.z), fabsf(v.w)));
}

// ---- K_PREP2: Whh INT4 quant (plain nibbles, chunked layout) + pre matvec ----
// Word j of a row covers cols 8j..8j+7; nibble k (bits 4k..4k+3) = col 8j+k,
// signed int4 in [-7,7]. Consumer uses v_dot8_i32_i4 against int4-packed h.
// Chunked layout: u32x4 chunk = which*8192 + c*1024 + ((hf<<9)|row), word wi:
// covers cols hf*256 + c*32 + wi*8 + [0..8).
__global__ __launch_bounds__(256) void k_prep2(
        const float* __restrict__ We,   const float* __restrict__ Wd,
        const int* __restrict__ fnums,  const int* __restrict__ enums,
        const float* __restrict__ emb_f,const float* __restrict__ emb_d,
        const float* __restrict__ Wih_e,const float* __restrict__ Wih_d,
        const float* __restrict__ b_e,  const float* __restrict__ b_d,
        uint32_t* __restrict__ q4, float* __restrict__ qsc,
        float* __restrict__ pre_e, float* __restrict__ pre_d) {
    __shared__ float xl[D];
    int bid = blockIdx.x, t = threadIdx.x;
    if (bid < 256) {                       // --- Whh int4 quant, 4 rows/block ---
        int rg = bid * 4 + (t >> 6);       // 0..1023
        int which = rg >> 9, row = rg & 511;
        int lane = t & 63;                 // word index: cols 8*lane..8*lane+7
        const float* W = which ? Wd : We;
        const float* src = W + (size_t)row * D + lane * 8;
        float w[8];
        #pragma unroll
        for (int k = 0; k < 8; k++) w[k] = src[k];
        float m = 0.f;
        #pragma unroll
        for (int k = 0; k < 8; k++) m = fmaxf(m, fabsf(w[k]));
        for (int off = 32; off; off >>= 1) m = fmaxf(m, __shfl_xor(m, off));
        float inv = (m > 0.f) ? 7.f / m : 0.f;
        uint32_t word = 0;
        #pragma unroll
        for (int k = 0; k < 8; k++) {
            int q = max(-7, min(7, __float2int_rn(w[k] * inv)));
            word |= ((uint32_t)(q & 0xF)) << (4 * k);
        }
        int hf = lane >> 5, c = (lane & 31) >> 2, wi = lane & 3;
        q4[((size_t)which * 8192 + (size_t)c * 1024 + (hf << 9) + row) * 4 + wi] = word;
        if (lane == 0) qsc[which * D + row] = m / 7.f;
    } else {                               // --- pre matvec (256 blocks) ---
        int bb = bid - 256;
        int kind = bb >> 7, s = bb & 127;
        const float* emb = kind ? emb_d : emb_f;
        int idx          = kind ? enums[s] : fnums[s];
        const float* W   = kind ? Wih_d : Wih_e;
        const float* b   = kind ? b_d : b_e;
        float* pre       = kind ? pre_d : pre_e;
        xl[t]       = emb[(size_t)idx * D + t];
        xl[t + 256] = emb[(size_t)idx * D + t + 256];
        __syncthreads();
        for (int rep = 0; rep < 2; rep++) {
            int o = t + rep * 256;
            float acc = b[o];
            const float4* Wr = (const float4*)(W + (size_t)o * D);
            #pragma unroll 8
            for (int k4 = 0; k4 < D / 4; k4++) {
                float4 w = Wr[k4];
                acc += w.x * xl[4*k4] + w.y * xl[4*k4+1] + w.z * xl[4*k4+2] + w.w * xl[4*k4+3];
            }
            pre[(size_t)s * D + o] = acc;
        }
    }
}

// ---- K2 (fused): blocks 0-1 = scans; blocks 2+ = Wm/Wo quant on idle CUs. ----
// Scan: int4 weights streamed from L2 (128 KB/step) x int4 h. Per lane/step:
// 1 ds_read_b32 (own h word) + 32 v_readlane + 32 v_dot8_i32_i4 (~75 VALU
// instr, half of r14's dot4 form). h packed to nibbles on the write side via
// shfl_xor pair + ds_write_b8. 2 barriers/step.
__global__ __launch_bounds__(1024)
__attribute__((amdgpu_waves_per_eu(4, 4)))
void k_scan_fused(
        const uint32_t* __restrict__ q4, const float* __restrict__ qsc,
        const float* __restrict__ pre_e, const float* __restrict__ pre_d,
        const float* __restrict__ h0_e, const float* __restrict__ h0_d,
        float* __restrict__ fencs, float* __restrict__ h2s,
        const float* __restrict__ Wm, const float* __restrict__ Wo,
        int8_t* __restrict__ wmq, float* __restrict__ wmsc,
        uint32_t* __restrict__ woq2, float* __restrict__ wosc) {
    __shared__ __align__(4) uint32_t hq4[2][64];   // int4 h, double-buffered
    __shared__ int pacc[D];                         // hf1 partial sums
    int bid = blockIdx.x, t = threadIdx.x;

    if (bid >= 2) {
        int lane = t & 63, sub = t >> 6;           // 16 rows/block, 64 lanes/row
        if (bid < 2 + WM16) {                      // --- Wm int8 quant ---
            int row = (bid - 2) * 16 + sub;        // 0..511
            const float4* src = (const float4*)(Wm + (size_t)row * 2 * D);
            float4 a = src[lane], b = src[lane + 64], c = src[lane + 128], d2 = src[lane + 192];
            float m = fmaxf(fmaxf(amax4(a), amax4(b)), fmaxf(amax4(c), amax4(d2)));
            for (int off = 32; off; off >>= 1) m = fmaxf(m, __shfl_xor(m, off));
            float inv = (m > 0.f) ? 127.f / m : 0.f;
            uint32_t* dst = (uint32_t*)(wmq + (size_t)row * 2 * D);
            dst[lane]       = pack4(a.x, a.y, a.z, a.w, inv);
            dst[lane + 64]  = pack4(b.x, b.y, b.z, b.w, inv);
            dst[lane + 128] = pack4(c.x, c.y, c.z, c.w, inv);
            dst[lane + 192] = pack4(d2.x, d2.y, d2.z, d2.w, inv);
            if (lane == 0) wmsc[row] = m / 127.f;
        } else {                                   // --- Wo int8 quant -> woq2 ---
            int row = (bid - 2 - WM16) * 16 + sub;
            if (row < EVOC) {
                const float4* src = (const float4*)(Wo + (size_t)row * D);
                float4 v0 = src[lane], v1 = src[lane + 64];
                float m = fmaxf(amax4(v0), amax4(v1));
                for (int off = 32; off; off >>= 1) m = fmaxf(m, __shfl_xor(m, off));
                float inv = (m > 0.f) ? 127.f / m : 0.f;
                uint32_t w1 = pack4(v0.x, v0.y, v0.z, v0.w, inv);
                uint32_t w2 = pack4(v1.x, v1.y, v1.z, v1.w, inv);
                int wA = lane, wB = lane + 64;
                woq2[((size_t)(row >> 7) * 4 + (wA >> 5)) * 4096 + (size_t)(row & 127) * 32 + (wA & 31)] = w1;
                woq2[((size_t)(row >> 7) * 4 + (wB >> 5)) * 4096 + (size_t)(row & 127) * 32 + (wB & 31)] = w2;
                if (lane == 0) wosc[row] = m / 127.f;
            }
        }
        return;
    }

    // ---- scan path (blocks 0,1) ----
    int lane = t & 63;
    int hf = t >> 9;                 // wave-uniform half selector
    int r  = t & 511;                // row
    int which = bid;
    const float* pre = which ? pre_d : pre_e;
    const float* h0  = which ? h0_d : h0_e;
    float*       hs  = which ? h2s : fencs;
    float sw = qsc[which * D + r] * (1.f / 7.f);   // (wmax/7) * (1/7)
    const u32x4* wq = (const u32x4*)q4 + (size_t)which * 8192 + t;

    if (hf == 0) {                   // init h0 -> int4 nibbles
        float h0v = fminf(fmaxf(h0[r], -0.999f), 0.999f);
        int nib = max(-7, min(7, __float2int_rn(h0v * 7.f)));
        uint32_t mynib = (uint32_t)(nib & 0xF);
        uint32_t other = (uint32_t)__shfl_xor((int)mynib, 1);
        if (!(r & 1))
            ((uint8_t*)&hq4[0][0])[r >> 1] = (uint8_t)(mynib | (other << 4));
    }
    __syncthreads();

    int p = 0;
    for (int step = 0; step < NSTEP; step++) {
        uint32_t own = hq4[p][(hf << 5) | (lane & 31)];   // one h word/lane
        int a0 = 0, a1 = 0;
        #pragma unroll
        for (int c = 0; c < 8; c++) {
            u32x4 wv = wq[c * 1024];               // coalesced 16B/lane from L2
            a0 = sdot8(wv.x, (uint32_t)rdlane(own, c * 4 + 0), a0);
            a1 = sdot8(wv.y, (uint32_t)rdlane(own, c * 4 + 1), a1);
            a0 = sdot8(wv.z, (uint32_t)rdlane(own, c * 4 + 2), a0);
            a1 = sdot8(wv.w, (uint32_t)rdlane(own, c * 4 + 3), a1);
        }
        int acc = a0 + a1;
        if (hf) pacc[r] = acc;
        __syncthreads();
        if (!hf) {
            int tot = acc + pacc[r];
            float h2 = tanhf(pre[(size_t)step * D + r] + (float)tot * sw);
            hs[(size_t)step * D + r] = h2;
            int nib = max(-7, min(7, __float2int_rn(h2 * 7.f)));
            uint32_t mynib = (uint32_t)(nib & 0xF);
            uint32_t other = (uint32_t)__shfl_xor((int)mynib, 1);
            if (!(r & 1))
                ((uint8_t*)&hq4[p ^ 1][0])[r >> 1] = (uint8_t)(mynib | (other << 4));
        }
        __syncthreads();
        p ^= 1;
    }
}

// ---- K3a: attention scores + softmax + context -> chq = int8 [c | h2] ----
__global__ __launch_bounds__(512) void k_att1(
        const float* __restrict__ fencs, const float* __restrict__ h2s,
        int8_t* __restrict__ chq) {
    __shared__ float h2l[D], sc[NSTEP], red[64];
    __shared__ float ftile[32 * D];
    int s = blockIdx.x, t = threadIdx.x;
    h2l[t] = h2s[(size_t)s * D + t];
    __syncthreads();

    {   // scores[j] = fencs[j] . h2 ; thread (j = t>>2, q = t&3)
        int j = t >> 2, q = t & 3;
        const float4* fr = (const float4*)(fencs + (size_t)j * D + q * 128);
        const float4* hr = (const float4*)(h2l + q * 128);
        float acc = 0.f;
        #pragma unroll 8
        for (int k4 = 0; k4 < 32; k4++) {
            float4 f = fr[k4], hh = hr[k4];
            acc += f.x*hh.x + f.y*hh.y + f.z*hh.z + f.w*hh.w;
        }
        acc += __shfl_xor(acc, 1);
        acc += __shfl_xor(acc, 2);
        if (q == 0) sc[j] = acc;
    }
    __syncthreads();
    if (t < 64) {
        float m = fmaxf(sc[t], sc[t + 64]);
        for (int off = 32; off; off >>= 1) m = fmaxf(m, __shfl_xor(m, off));
        if (t == 0) red[0] = m;
    }
    __syncthreads();
    float mx = red[0];
    __syncthreads();
    if (t < NSTEP) sc[t] = expf(sc[t] - mx);
    __syncthreads();
    if (t < 64) {
        float v = sc[t] + sc[t + 64];
        for (int off = 32; off; off >>= 1) v += __shfl_xor(v, off);
        if (t == 0) red[0] = v;
    }
    __syncthreads();
    float inv = 1.0f / red[0];

    float cacc = 0.f;
    for (int jt = 0; jt < 4; jt++) {
        #pragma unroll
        for (int k = 0; k < 32; k++)
            ftile[t + k * D] = fencs[(size_t)jt * 32 * D + t + k * D];
        __syncthreads();
        #pragma unroll 8
        for (int j = 0; j < 32; j++)
            cacc += sc[jt * 32 + j] * ftile[j * D + t];
        __syncthreads();
    }
    float cv = cacc * inv;
    chq[(size_t)s * 2 * D + t]     = (int8_t)__float2int_rn(cv * 127.f);
    chq[(size_t)s * 2 * D + D + t] = (int8_t)__float2int_rn(h2l[t] * 127.f);
}

// ---- K3b: m = tanh([c,h2] @ Wm^T + bm) as ONE int8 GEMM (Wm read once) ----
__global__ __launch_bounds__(512) void k_att2(
        const int8_t* __restrict__ chq, const int8_t* __restrict__ wmq,
        const float* __restrict__ wmsc, const float* __restrict__ bm,
        int8_t* __restrict__ mq) {
    __shared__ __align__(16) uint32_t a_s[128 * LDA_W];
    __shared__ __align__(16) uint32_t b_s[32 * LDB_W];
    int t = threadIdx.x;
    int v0 = blockIdx.x * VTILE;
    int ti = t >> 5, tj = t & 31;
    int lrow = t >> 3, lq = t & 7;
    int acc[8][4] = {};

    for (int kc = 0; kc < 8; kc++) {
        #pragma unroll
        for (int rep = 0; rep < 2; rep++) {
            int row = lrow + rep * 64;
            uint4 av = *(const uint4*)(chq + (size_t)row * 2 * D + kc * 128 + lq * 16);
            *(uint4*)&a_s[row * LDA_W + lq * 4] = av;
            int v = v0 + row;
            uint4 bv = *(const uint4*)(wmq + (size_t)v * 2 * D + kc * 128 + lq * 16);
            b_s[(lq*4+0) * LDB_W + row] = bv.x;
            b_s[(lq*4+1) * LDB_W + row] = bv.y;
            b_s[(lq*4+2) * LDB_W + row] = bv.z;
            b_s[(lq*4+3) * LDB_W + row] = bv.w;
        }
        __syncthreads();
        #pragma unroll
        for (int q = 0; q < 8; q++) {
            uint4 aw[8];
            #pragma unroll
            for (int i = 0; i < 8; i++)
                aw[i] = *(const uint4*)&a_s[(ti*8 + i) * LDA_W + q*4];
            #pragma unroll
            for (int k4 = 0; k4 < 4; k4++) {
                uint4 bw = *(const uint4*)&b_s[(q*4 + k4) * LDB_W + tj * 4];
                #pragma unroll
                for (int i = 0; i < 8; i++) {
                    uint32_t a = (k4 == 0) ? aw[i].x : (k4 == 1) ? aw[i].y
                               : (k4 == 2) ? aw[i].z : aw[i].w;
                    acc[i][0] = sdot4((int)a, (int)bw.x, acc[i][0]);
                    acc[i][1] = sdot4((int)a, (int)bw.y, acc[i][1]);
                    acc[i][2] = sdot4((int)a, (int)bw.z, acc[i][2]);
                    acc[i][3] = sdot4((int)a, (int)bw.w, acc[i][3]);
                }
            }
        }
        __syncthreads();
    }

    float sw4[4], bm4[4];
    #pragma unroll
    for (int jj = 0; jj < 4; jj++) {
        int col = v0 + tj * 4 + jj;
        sw4[jj] = wmsc[col] * (1.f / (127.f * 127.f));
        bm4[jj] = bm[col];
    }
    #pragma unroll
    for (int i = 0; i < 8; i++) {
        int s = ti * 8 + i;
        float m0 = tanhf((float)acc[i][0] * sw4[0] + bm4[0]);
        float m1 = tanhf((float)acc[i][1] * sw4[1] + bm4[1]);
        float m2 = tanhf((float)acc[i][2] * sw4[2] + bm4[2]);
        float m3 = tanhf((float)acc[i][3] * sw4[3] + bm4[3]);
        ((uint32_t*)mq)[(size_t)s * (D / 4) + (v0 >> 2) + tj] = pack4(m0, m1, m2, m3, 127.f);
    }
}

// ---- K4: int8 logits GEMM + fused row max/sumexp ----
__global__ __launch_bounds__(512) void k_logits(
        const int8_t* __restrict__ mq, const uint32_t* __restrict__ woq2,
        const float* __restrict__ wosc, const float* __restrict__ bo,
        const int* __restrict__ enums,
        float* __restrict__ pmax, float* __restrict__ psum, float* __restrict__ pick) {
    __shared__ __align__(16) uint32_t a_s[128 * LDA_W];
    __shared__ __align__(16) uint32_t b_s[32 * LDB_W];
    int b = blockIdx.x, t = threadIdx.x;
    int v0 = b * VTILE;
    int ti = t >> 5, tj = t & 31;
    int lrow = t >> 3, lq = t & 7;
    int acc[8][4] = {};

    for (int kc = 0; kc < 4; kc++) {
        const uint4* bsrc = (const uint4*)(woq2 + ((size_t)b * 4 + kc) * 4096);
        #pragma unroll
        for (int rep = 0; rep < 2; rep++) {
            int row = lrow + rep * 64;
            uint4 av = *(const uint4*)(mq + (size_t)row * D + kc * 128 + lq * 16);
            *(uint4*)&a_s[row * LDA_W + lq * 4] = av;
            uint4 bv = bsrc[t + rep * 512];
            b_s[(lq*4+0) * LDB_W + row] = bv.x;
            b_s[(lq*4+1) * LDB_W + row] = bv.y;
            b_s[(lq*4+2) * LDB_W + row] = bv.z;
            b_s[(lq*4+3) * LDB_W + row] = bv.w;
        }
        __syncthreads();
        #pragma unroll
        for (int q = 0; q < 8; q++) {
            uint4 aw[8];
            #pragma unroll
            for (int i = 0; i < 8; i++)
                aw[i] = *(const uint4*)&a_s[(ti*8 + i) * LDA_W + q*4];
            #pragma unroll
            for (int k4 = 0; k4 < 4; k4++) {
                uint4 bw = *(const uint4*)&b_s[(q*4 + k4) * LDB_W + tj * 4];
                #pragma unroll
                for (int i = 0; i < 8; i++) {
                    uint32_t a = (k4 == 0) ? aw[i].x : (k4 == 1) ? aw[i].y
                               : (k4 == 2) ? aw[i].z : aw[i].w;
                    acc[i][0] = sdot4((int)a, (int)bw.x, acc[i][0]);
                    acc[i][1] = sdot4((int)a, (int)bw.y, acc[i][1]);
                    acc[i][2] = sdot4((int)a, (int)bw.z, acc[i][2]);
                    acc[i][3] = sdot4((int)a, (int)bw.w, acc[i][3]);
                }
            }
        }
        __syncthreads();
    }

    float sw4[4], bo4[4];
    int vld[4];
    #pragma unroll
    for (int jj = 0; jj < 4; jj++) {
        int v = v0 + tj * 4 + jj;
        vld[jj] = (v < EVOC);
        sw4[jj] = vld[jj] ? wosc[v] * (1.f / 127.f) : 0.f;
        bo4[jj] = vld[jj] ? bo[v] : 0.f;
    }
    #pragma unroll
    for (int i = 0; i < 8; i++) {
        int s = ti * 8 + i;
        float l[4];
        float mx = -1e30f;
        #pragma unroll
        for (int jj = 0; jj < 4; jj++) {
            l[jj] = vld[jj] ? (float)acc[i][jj] * sw4[jj] + bo4[jj] : -1e30f;
            mx = fmaxf(mx, l[jj]);
        }
        #pragma unroll
        for (int off = 1; off < 32; off <<= 1) mx = fmaxf(mx, __shfl_xor(mx, off));
        float sm = 0.f;
        #pragma unroll
        for (int jj = 0; jj < 4; jj++)
            if (vld[jj]) sm += expf(l[jj] - mx);
        #pragma unroll
        for (int off = 1; off < 32; off <<= 1) sm += __shfl_xor(sm, off);
        if (tj == 0) { pmax[b * NSTEP + s] = mx; psum[b * NSTEP + s] = sm; }
        int tgt = enums[s + 1];
        if (tgt >= v0 && tgt < v0 + VTILE) {
            int c = tgt - v0;
            if ((c >> 2) == tj) pick[s] = l[c & 3];
        }
    }
}

// ---- K5a: per-step logsumexp combine, 128 blocks in parallel ----
__global__ __launch_bounds__(256) void k_final_par(
        const float* __restrict__ pmax, const float* __restrict__ psum,
        const float* __restrict__ pick, float* __restrict__ lp) {
    __shared__ float red[8];
    int s = blockIdx.x, t = threadIdx.x;
    float M = -1e30f;
    for (int b = t; b < NBV; b += 256) M = fmaxf(M, pmax[b * NSTEP + s]);
    for (int off = 32; off; off >>= 1) M = fmaxf(M, __shfl_xor(M, off));
    if ((t & 63) == 0) red[t >> 6] = M;
    __syncthreads();
    M = fmaxf(fmaxf(red[0], red[1]), fmaxf(red[2], red[3]));
    float S = 0.f;
    for (int b = t; b < NBV; b += 256) S += psum[b * NSTEP + s] * expf(pmax[b * NSTEP + s] - M);
    for (int off = 32; off; off >>= 1) S += __shfl_xor(S, off);
    if ((t & 63) == 0) red[4 + (t >> 6)] = S;
    __syncthreads();
    if (t == 0) {
        S = red[4] + red[5] + red[6] + red[7];
        lp[s] = pick[s] - (M + logf(S));
    }
}

// ---- K5b: sum 128 logprobs ----
__global__ void k_final_sum(const float* __restrict__ lp, float* __restrict__ out) {
    __shared__ float red[NSTEP];
    int t = threadIdx.x;
    red[t] = lp[t];
    __syncthreads();
    for (int off = 64; off > 0; off >>= 1) {
        if (t < off) red[t] += red[t + off];
        __syncthreads();
    }
    if (t == 0) out[0] = red[0];
}

extern "C" void kernel_launch(void* const* d_in, const int* in_sizes, int n_in,
                              void* d_out, int out_size, void* d_ws, size_t ws_size,
                              hipStream_t stream) {
    const int*   fnums = (const int*)  d_in[0];
    const int*   enums = (const int*)  d_in[1];
    const float* emb_f = (const float*)d_in[2];
    const float* Wih_e = (const float*)d_in[3];
    const float* Whh_e = (const float*)d_in[4];
    const float* b_e   = (const float*)d_in[5];
    const float* h0_e  = (const float*)d_in[6];
    const float* emb_d = (const float*)d_in[7];
    const float* Wih_d = (const float*)d_in[8];
    const float* Whh_d = (const float*)d_in[9];
    const float* b_d   = (const float*)d_in[10];
    const float* h0_d  = (const float*)d_in[11];
    const float* Wm    = (const float*)d_in[12];
    const float* bm    = (const float*)d_in[13];
    const float* Wo    = (const float*)d_in[14];
    const float* bo    = (const float*)d_in[15];

    float* ws = (float*)d_ws;
    float* pre_e = ws;                        // 65536
    float* pre_d = ws + 65536;                // 65536
    float* fencs = ws + 131072;               // 65536
    float* h2s   = ws + 196608;               // 65536
    float* pmax  = ws + 262144;               // 50048
    float* psum  = ws + 312192;               // 50048
    float* pick  = ws + 362240;               // 128
    float* lp    = ws + 362368;               // 128
    float* qsc   = ws + 362496;               // 1024
    float* wmsc  = ws + 363520;               // 512
    float* wosc  = ws + 364032;               // 50048
    uint32_t* q4 = (uint32_t*)(ws + 414080);  // 65536 u32 = 256 KB int4 scan weights
    int8_t*   wmq  = (int8_t*)(ws + 479616);  // 512 KB
    int8_t*   chq  = (int8_t*)(ws + 610688);  // 128 KB
    int8_t*   mq   = (int8_t*)(ws + 643456);  // 64 KB
    uint32_t* woq2 = (uint32_t*)(ws + 659840);// 391*16384 u32 = 25.6 MB (padded)

    k_prep2<<<dim3(512), dim3(256), 0, stream>>>(
        Whh_e, Whh_d, fnums, enums, emb_f, emb_d, Wih_e, Wih_d, b_e, b_d,
        q4, qsc, pre_e, pre_d);
    k_scan_fused<<<dim3(2 + WM16 + WO16), dim3(1024), 0, stream>>>(
        q4, qsc, pre_e, pre_d, h0_e, h0_d, fencs, h2s,
        Wm, Wo, wmq, wmsc, woq2, wosc);
    k_att1<<<dim3(NSTEP), dim3(512), 0, stream>>>(fencs, h2s, chq);
    k_att2<<<dim3(4), dim3(512), 0, stream>>>(chq, wmq, wmsc, bm, mq);
    k_logits<<<dim3(NBV), dim3(512), 0, stream>>>(mq, woq2, wosc, bo, enums, pmax, psum, pick);
    k_final_par<<<dim3(NSTEP), dim3(256), 0, stream>>>(pmax, psum, pick, lp);
    k_final_sum<<<dim3(1), dim3(NSTEP), 0, stream>>>(lp, (float*)d_out);
}